// Round 1
// baseline (4224.651 us; speedup 1.0000x reference)
//
#include <hip/hip_runtime.h>
#include <hip/hip_fp16.h>
#include <cstdint>
#include <cstddef>

// ---------------- problem constants ----------------
#define B_  2
#define S_  1024
#define D_  4096
#define KV_ 1024
#define F_  14336
#define H_  32
#define HK_ 8
#define HD_ 128
#define M_  2048   // B*S

typedef _Float16 f16;
typedef f16   f16x8 __attribute__((ext_vector_type(8)));
typedef f16   f16x4 __attribute__((ext_vector_type(4)));
typedef float f32x4 __attribute__((ext_vector_type(4)));

#define AS1(p) ((const __attribute__((address_space(1))) void*)(p))
#define AS3(p) ((__attribute__((address_space(3))) void*)(p))

__device__ __constant__ float NF4_C[16] = {
 -1.0f, -0.6961928009986877f, -0.5250730514526367f, -0.39491748809814453f,
 -0.28444138169288635f, -0.18477343022823334f, -0.09105003625154495f, 0.0f,
 0.07958029955625534f, 0.16093020141124725f, 0.24611230194568634f,
 0.33791524171829224f, 0.44070982933044434f, 0.5626170039176941f,
 0.7229568362236023f, 1.0f };

// ---------------- dtype detection (u8 vs i32 idx arrays) ----------------
__global__ void k_detect(const unsigned* __restrict__ p, int* __restrict__ flag){
    if (threadIdx.x == 0){
        int u8 = 0;
        for (int i = 0; i < 256; ++i) if (p[i] >= 16u) { u8 = 1; break; }
        *flag = u8;   // 1 => bytes, 0 => int32 values
    }
}

// ---------------- NF4 dequant: idx -> f16 weights ----------------
// thread handles 16 elements; grid = n/4096 (all n divisible by 4096)
__global__ __launch_bounds__(256) void k_dequant(const void* __restrict__ idxBase, size_t elemOff,
        const float* __restrict__ amax, f16* __restrict__ out, const int* __restrict__ flag)
{
    __shared__ __half2 T[3856];
    int t = threadIdx.x;
    if (t < 256){
        int b0 = t & 15, b1 = t >> 4;
        T[b0 + (b1 << 8)] = __halves2half2(__float2half(NF4_C[b0]), __float2half(NF4_C[b1]));
    }
    __syncthreads();
    size_t i = ((size_t)blockIdx.x * 256 + t) * 16;
    float am = amax[i >> 6];
    __half2 am2 = __float2half2_rn(am);
    union { __half2 h2[8]; uint4 u4[2]; } R;
    if (*flag){
        uint4 u = *(const uint4*)((const uint8_t*)idxBase + elemOff + i);
        unsigned w[4] = {u.x, u.y, u.z, u.w};
        #pragma unroll
        for (int j = 0; j < 4; ++j){
            R.h2[j*2+0] = __hmul2(T[w[j] & 0xFFFFu], am2);
            R.h2[j*2+1] = __hmul2(T[w[j] >> 16],     am2);
        }
    } else {
        const int4* s4 = (const int4*)((const int*)idxBase + elemOff + i);
        #pragma unroll
        for (int j = 0; j < 4; ++j){
            int4 a = s4[j];
            R.h2[j*2+0] = __hmul2(T[a.x | (a.y << 8)], am2);
            R.h2[j*2+1] = __hmul2(T[a.z | (a.w << 8)], am2);
        }
    }
    uint4* o = (uint4*)(out + i);
    o[0] = R.u4[0]; o[1] = R.u4[1];
}

// ---------------- embedding gather (fp32) ----------------
__global__ __launch_bounds__(256) void k_embed(const int* __restrict__ ids,
        const float* __restrict__ E, float* __restrict__ Hh)
{
    int row = blockIdx.x, t = threadIdx.x;
    int id = ids[row];
    const float4* s4 = (const float4*)(E + (size_t)id * D_);
    float4* d4 = (float4*)(Hh + (size_t)row * D_);
    #pragma unroll
    for (int i = 0; i < 4; ++i) d4[t + 256*i] = s4[t + 256*i];
}

// ---------------- RoPE tables ----------------
__global__ __launch_bounds__(256) void k_ropetab(float* __restrict__ cosT, float* __restrict__ sinT){
    int id = blockIdx.x * 256 + threadIdx.x;     // id = s*64 + d, 65536 total
    int d = id & 63, s = id >> 6;
    float inv = powf(500000.0f, -(float)d * (1.0f/64.0f));
    float ang = (float)s * inv;
    cosT[id] = cosf(ang);
    sinT[id] = sinf(ang);
}

// ---------------- RMSNorm (fp32 in, f16 or fp32 out) ----------------
template<int F16OUT>
__global__ __launch_bounds__(256) void k_rmsnorm(const float* __restrict__ X,
        const float* __restrict__ W, void* __restrict__ outv)
{
    int row = blockIdx.x, t = threadIdx.x;
    const float4* x4 = (const float4*)(X + (size_t)row * D_);
    float4 xs[4]; float ss = 0.f;
    #pragma unroll
    for (int i = 0; i < 4; ++i){
        xs[i] = x4[t + 256*i];
        ss += xs[i].x*xs[i].x + xs[i].y*xs[i].y + xs[i].z*xs[i].z + xs[i].w*xs[i].w;
    }
    for (int m = 32; m; m >>= 1) ss += __shfl_xor(ss, m, 64);
    __shared__ float red[4];
    if ((t & 63) == 0) red[t >> 6] = ss;
    __syncthreads();
    ss = red[0] + red[1] + red[2] + red[3];
    float rs = rsqrtf(ss * (1.0f / D_) + 1e-5f);
    #pragma unroll
    for (int i = 0; i < 4; ++i){
        int c0 = (t + 256*i) * 4;
        float4 wv = *(const float4*)(W + c0);
        float o0 = xs[i].x*rs*wv.x, o1 = xs[i].y*rs*wv.y;
        float o2 = xs[i].z*rs*wv.z, o3 = xs[i].w*rs*wv.w;
        if (F16OUT){
            f16x4 ov = { (f16)o0, (f16)o1, (f16)o2, (f16)o3 };
            *(f16x4*)((f16*)outv + (size_t)row * D_ + c0) = ov;
        } else {
            float4 ov = {o0, o1, o2, o3};
            *(float4*)((float*)outv + (size_t)row * D_ + c0) = ov;
        }
    }
}

// ---------------- RoPE apply + [b,s,h,d] -> [b,h,s,d] ----------------
template<int LNH>
__global__ __launch_bounds__(256) void k_rope(const f16* __restrict__ in, f16* __restrict__ outp,
        const float* __restrict__ cosT, const float* __restrict__ sinT)
{
    int p = blockIdx.x * 256 + threadIdx.x;
    int d = p & 63;
    int h = (p >> 6) & ((1 << LNH) - 1);
    int s = (p >> (6 + LNH)) & (S_ - 1);
    int b = p >> (16 + LNH);
    size_t ib = (((size_t)(b * S_ + s) << LNH) + (size_t)h) * HD_;
    float x1 = (float)in[ib + d], x2 = (float)in[ib + 64 + d];
    float c = cosT[s*64 + d], sn = sinT[s*64 + d];
    size_t ob = (((size_t)((b << LNH) + h)) * S_ + (size_t)s) * HD_;
    outp[ob + d]      = (f16)(x1 * c - x2 * sn);
    outp[ob + 64 + d] = (f16)(x2 * c + x1 * sn);
}

// ---------------- V: [b,s,hk,d] -> [b,hk,d,s] (transposed for PV GEMM) ----------------
__global__ __launch_bounds__(256) void k_vtrans(const f16* __restrict__ in, f16* __restrict__ outp){
    int p = blockIdx.x * 256 + threadIdx.x;   // 2^21 total
    int s  = p & (S_ - 1);
    int d  = (p >> 10) & (HD_ - 1);
    int hk = (p >> 17) & (HK_ - 1);
    int b  = p >> 20;
    f16 v = in[(((size_t)(b * S_ + s)) * HK_ + hk) * HD_ + d];
    outp[(((size_t)(b * HK_ + hk)) * HD_ + d) * S_ + s] = v;
}

// ---------------- causal softmax, in-place on f16 scores ----------------
__global__ __launch_bounds__(256) void k_softmax(__half* __restrict__ P, const int* __restrict__ amask, int bh0){
    int rid = blockIdx.x;
    int z = rid >> 10, sq = rid & (S_ - 1);
    int b = (bh0 + z) >> 5;
    __half* row = P + (size_t)z * S_ * S_ + (size_t)sq * S_;
    int t = threadIdx.x;
    const __half2* r2 = (const __half2*)row;
    __half2 a0 = r2[t*2], a1 = r2[t*2 + 1];
    float v[4] = { __low2float(a0), __high2float(a0), __low2float(a1), __high2float(a1) };
    int c0 = t * 4;
    #pragma unroll
    for (int j = 0; j < 4; ++j){
        int col = c0 + j;
        if (col > sq || amask[b * S_ + col] == 0) v[j] = -1e30f;
    }
    float mx = fmaxf(fmaxf(v[0], v[1]), fmaxf(v[2], v[3]));
    for (int m = 32; m; m >>= 1) mx = fmaxf(mx, __shfl_xor(mx, m, 64));
    __shared__ float red[4];
    if ((t & 63) == 0) red[t >> 6] = mx;
    __syncthreads();
    mx = fmaxf(fmaxf(red[0], red[1]), fmaxf(red[2], red[3]));
    float p4[4], sum = 0.f;
    #pragma unroll
    for (int j = 0; j < 4; ++j){ p4[j] = __expf(v[j] - mx); sum += p4[j]; }
    for (int m = 32; m; m >>= 1) sum += __shfl_xor(sum, m, 64);
    __syncthreads();
    if ((t & 63) == 0) red[t >> 6] = sum;
    __syncthreads();
    sum = red[0] + red[1] + red[2] + red[3];
    float inv = 1.0f / fmaxf(sum, 1e-30f);
    __half2* w2 = (__half2*)row;
    w2[t*2]     = __floats2half2_rn(p4[0]*inv, p4[1]*inv);
    w2[t*2 + 1] = __floats2half2_rn(p4[2]*inv, p4[3]*inv);
}

// ---------------- generic MFMA GEMM: C[M,N] (+=) A[M,K] * B[N,K]^T ----------------
// OUT: 0 = fp32 store, 1 = fp32 +=, 2 = f16 store (scaled), 3 = f16 silu(G)*acc
// BM : 0 = plain, 1 = attention scores batch, 2 = attention PV batch
template<int OUT, int BM>
__global__ __launch_bounds__(256) void k_gemm(const f16* __restrict__ A, const f16* __restrict__ Bp,
        void* __restrict__ Cv, const f16* __restrict__ G,
        int Kd, int ldc, float scale, int bh0)
{
    __shared__ f16 As[128 * 64];
    __shared__ f16 Bs[128 * 64];
    int t = threadIdx.x;
    int wave = t >> 6, lane = t & 63;
    int wr = wave >> 1, wc = wave & 1;
    int lr = lane & 15, lg = lane >> 4;
    int row0 = blockIdx.y * 128, col0 = blockIdx.x * 128;

    size_t aOff = 0, bOff = 0, cOff = 0;
    if (BM == 1){
        int bh = bh0 + blockIdx.z;
        aOff = (size_t)bh * (S_ * HD_);
        bOff = (size_t)((bh >> 5) * HK_ + ((bh & 31) >> 2)) * (S_ * HD_);
        cOff = (size_t)blockIdx.z * (S_ * S_);
    } else if (BM == 2){
        int bh = bh0 + blockIdx.z;
        aOff = (size_t)blockIdx.z * (S_ * S_);
        bOff = (size_t)((bh >> 5) * HK_ + ((bh & 31) >> 2)) * (HD_ * S_);
        cOff = (size_t)(bh >> 5) * ((size_t)S_ * D_) + (size_t)(bh & 31) * HD_;
    }

    f32x4 zero = {0.f, 0.f, 0.f, 0.f};
    f32x4 acc[4][4];
    #pragma unroll
    for (int m = 0; m < 4; ++m)
        #pragma unroll
        for (int n = 0; n < 4; ++n) acc[m][n] = zero;

    int srow = lane >> 3;          // 0..7
    int scol = (lane & 7) * 8;     // f16 element within row
    const f16* Abase = A  + aOff + (size_t)row0 * Kd;
    const f16* Bbase = Bp + bOff + (size_t)col0 * Kd;

    for (int k0 = 0; k0 < Kd; k0 += 64){
        if (k0) __syncthreads();
        #pragma unroll
        for (int i = 0; i < 4; ++i){
            int chunk = wave * 4 + i;          // 16 chunks x 1KB each
            int r = chunk * 8 + srow;          // tile row 0..127
            __builtin_amdgcn_global_load_lds(AS1(Abase + (size_t)r * Kd + k0 + scol), AS3(&As[chunk * 512]), 16, 0, 0);
            __builtin_amdgcn_global_load_lds(AS1(Bbase + (size_t)r * Kd + k0 + scol), AS3(&Bs[chunk * 512]), 16, 0, 0);
        }
        __syncthreads();
        #pragma unroll
        for (int kk = 0; kk < 64; kk += 32){
            f16x8 av[4], bv[4];
            #pragma unroll
            for (int m = 0; m < 4; ++m) av[m] = *(const f16x8*)&As[(wr*64 + m*16 + lr)*64 + kk + lg*8];
            #pragma unroll
            for (int n = 0; n < 4; ++n) bv[n] = *(const f16x8*)&Bs[(wc*64 + n*16 + lr)*64 + kk + lg*8];
            #pragma unroll
            for (int m = 0; m < 4; ++m)
                #pragma unroll
                for (int n = 0; n < 4; ++n)
                    acc[m][n] = __builtin_amdgcn_mfma_f32_16x16x32_f16(av[m], bv[n], acc[m][n], 0, 0, 0);
        }
    }

    // epilogue: C/D layout col = lane&15, row = (lane>>4)*4 + reg  [m89-verified]
    #pragma unroll
    for (int m = 0; m < 4; ++m)
    #pragma unroll
    for (int n = 0; n < 4; ++n)
    #pragma unroll
    for (int r = 0; r < 4; ++r){
        int row = row0 + wr*64 + m*16 + lg*4 + r;
        int col = col0 + wc*64 + n*16 + lr;
        size_t idx = cOff + (size_t)row * ldc + col;
        float v = acc[m][n][r] * scale;
        if (OUT == 0)      ((float*)Cv)[idx] = v;
        else if (OUT == 1) ((float*)Cv)[idx] += v;
        else if (OUT == 2) ((f16*)Cv)[idx] = (f16)v;
        else {
            float g = (float)G[idx];
            float sg = g / (1.f + __expf(-g));
            ((f16*)Cv)[idx] = (f16)(sg * v);
        }
    }
}

// ---------------- masked mean pool ----------------
__global__ __launch_bounds__(256) void k_pool(const float* __restrict__ Hn, const int* __restrict__ amask,
        float* __restrict__ outp)
{
    int gid = blockIdx.x * 256 + threadIdx.x;   // B*D = 8192
    int b = gid >> 12, d = gid & (D_ - 1);
    float s = 0.f, cnt = 0.f;
    for (int i = 0; i < S_; ++i){
        if (amask[b * S_ + i]){
            s += Hn[((size_t)(b * S_ + i)) * D_ + d];
            cnt += 1.f;
        }
    }
    outp[gid] = s / fmaxf(cnt, 1e-9f);
}

// ---------------- launch ----------------
extern "C" void kernel_launch(void* const* d_in, const int* in_sizes, int n_in,
                              void* d_out, int out_size, void* d_ws, size_t ws_size,
                              hipStream_t stream)
{
    (void)in_sizes; (void)n_in; (void)out_size; (void)ws_size;
    const int*   ids   = (const int*)  d_in[0];
    const int*   amask = (const int*)  d_in[1];
    const float* embed = (const float*)d_in[2];
    const void*  qi = d_in[3];  const float* qa = (const float*)d_in[4];
    const void*  ki = d_in[5];  const float* ka = (const float*)d_in[6];
    const void*  vi = d_in[7];  const float* va = (const float*)d_in[8];
    const void*  oi = d_in[9];  const float* oa = (const float*)d_in[10];
    const void*  gi = d_in[11]; const float* ga = (const float*)d_in[12];
    const void*  ui = d_in[13]; const float* ua = (const float*)d_in[14];
    const void*  di = d_in[15]; const float* da = (const float*)d_in[16];
    const float* ln1 = (const float*)d_in[17];
    const float* ln2 = (const float*)d_in[18];
    const float* lnf = (const float*)d_in[19];

    const size_t DD  = (size_t)D_ * D_;       // 16,777,216
    const size_t KVD = (size_t)KV_ * D_;      //  4,194,304
    const size_t FD  = (size_t)F_ * D_;       // 58,720,256

    // workspace layout (bytes, all 256-aligned); total ~302.5 MB
    char* ws = (char*)d_ws;
    int*   flag = (int*)ws;
    float* h    = (float*)(ws + 256);                         // 33,554,432
    float* cosT = (float*)(ws + 256 + 33554432);              //    262,144
    float* sinT = cosT + 65536;                               //    262,144
    f16*   xin  = (f16*)(ws + 34078976);                      // 16,777,216
    f16*   wbuf = (f16*)(ws + 50856192);                      // 117,440,512
    char*  R4   = ws + 168296704;                             // 67,108,864 region
    f16* q16 = (f16*)(R4);
    f16* k16 = (f16*)(R4 + 16777216);
    f16* v16 = (f16*)(R4 + 20971520);
    f16* qr  = (f16*)(R4 + 25165824);
    f16* kr  = (f16*)(R4 + 41943040);
    f16* vtr = (f16*)(R4 + 46137344);
    f16* ctx = (f16*)(R4 + 50331648);
    char* R5 = R4 + 67108864;                                 // 67,108,864 region
    __half* scores = (__half*)R5;          // 32-bh chunk of attention probs
    f16*    gbuf   = (f16*)R5;             // MLP gate / silu*up (in-place)
    float*  hn     = (float*)R4;           // final normed h (R4 dead by then)

    const float ISQ = 0.08838834764831845f;  // 1/sqrt(128)

    k_detect <<<1, 64, 0, stream>>>((const unsigned*)qi, flag);
    k_embed  <<<M_, 256, 0, stream>>>(ids, embed, h);
    k_ropetab<<<256, 256, 0, stream>>>(cosT, sinT);

    for (int l = 0; l < 2; ++l){
        size_t oDD = (size_t)l * DD, oKVD = (size_t)l * KVD, oFD = (size_t)l * FD;
        k_rmsnorm<1><<<M_, 256, 0, stream>>>(h, ln1 + l * D_, xin);

        // Q / K / V projections
        k_dequant<<<DD / 4096, 256, 0, stream>>>(qi, oDD, qa + oDD/64, wbuf, flag);
        k_gemm<2,0><<<dim3(D_/128, M_/128, 1), 256, 0, stream>>>(xin, wbuf, q16, nullptr, D_, D_, 1.0f, 0);
        k_dequant<<<KVD / 4096, 256, 0, stream>>>(ki, oKVD, ka + oKVD/64, wbuf, flag);
        k_gemm<2,0><<<dim3(KV_/128, M_/128, 1), 256, 0, stream>>>(xin, wbuf, k16, nullptr, D_, KV_, 1.0f, 0);
        k_dequant<<<KVD / 4096, 256, 0, stream>>>(vi, oKVD, va + oKVD/64, wbuf, flag);
        k_gemm<2,0><<<dim3(KV_/128, M_/128, 1), 256, 0, stream>>>(xin, wbuf, v16, nullptr, D_, KV_, 1.0f, 0);

        // RoPE + layout changes
        k_rope<5><<<(B_*S_*H_*64)/256, 256, 0, stream>>>(q16, qr, cosT, sinT);
        k_rope<3><<<(B_*S_*HK_*64)/256, 256, 0, stream>>>(k16, kr, cosT, sinT);
        k_vtrans <<<(B_*HK_*HD_*S_)/256, 256, 0, stream>>>(v16, vtr);

        // attention in 2 chunks of 32 (b,h) pairs
        for (int c = 0; c < 2; ++c){
            k_gemm<2,1><<<dim3(S_/128, S_/128, 32), 256, 0, stream>>>(qr, kr, (void*)scores, nullptr, HD_, S_, ISQ, c*32);
            k_softmax<<<32 * S_, 256, 0, stream>>>(scores, amask, c*32);
            k_gemm<2,2><<<dim3(1, S_/128, 32), 256, 0, stream>>>((const f16*)scores, vtr, ctx, nullptr, S_, D_, 1.0f, c*32);
        }

        // O projection + residual (in-place on h)
        k_dequant<<<DD / 4096, 256, 0, stream>>>(oi, oDD, oa + oDD/64, wbuf, flag);
        k_gemm<1,0><<<dim3(D_/128, M_/128, 1), 256, 0, stream>>>(ctx, wbuf, h, nullptr, D_, D_, 1.0f, 0);

        // MLP
        k_rmsnorm<1><<<M_, 256, 0, stream>>>(h, ln2 + l * D_, xin);
        k_dequant<<<FD / 4096, 256, 0, stream>>>(gi, oFD, ga + oFD/64, wbuf, flag);
        k_gemm<2,0><<<dim3(F_/128, M_/128, 1), 256, 0, stream>>>(xin, wbuf, gbuf, nullptr, D_, F_, 1.0f, 0);
        k_dequant<<<FD / 4096, 256, 0, stream>>>(ui, oFD, ua + oFD/64, wbuf, flag);
        k_gemm<3,0><<<dim3(F_/128, M_/128, 1), 256, 0, stream>>>(xin, wbuf, gbuf, gbuf, D_, F_, 1.0f, 0);
        k_dequant<<<FD / 4096, 256, 0, stream>>>(di, oFD, da + oFD/64, wbuf, flag);
        k_gemm<1,0><<<dim3(D_/128, M_/128, 1), 256, 0, stream>>>(gbuf, wbuf, h, nullptr, F_, D_, 1.0f, 0);
    }

    k_rmsnorm<0><<<M_, 256, 0, stream>>>(h, lnf, hn);
    k_pool<<<(B_*D_)/256, 256, 0, stream>>>(hn, amask, (float*)d_out);
}

// Round 2
// 3744.952 us; speedup vs baseline: 1.1281x; 1.1281x over previous
//
#include <hip/hip_runtime.h>
#include <hip/hip_fp16.h>
#include <cstdint>
#include <cstddef>

// ---------------- problem constants ----------------
#define B_  2
#define S_  1024
#define D_  4096
#define KV_ 1024
#define F_  14336
#define H_  32
#define HK_ 8
#define HD_ 128
#define M_  2048   // B*S

typedef _Float16 f16;
typedef f16   f16x8 __attribute__((ext_vector_type(8)));
typedef f16   f16x4 __attribute__((ext_vector_type(4)));
typedef float f32x4 __attribute__((ext_vector_type(4)));

#define AS1(p) ((const __attribute__((address_space(1))) void*)(p))
#define AS3(p) ((__attribute__((address_space(3))) void*)(p))

__device__ __constant__ float NF4_C[16] = {
 -1.0f, -0.6961928009986877f, -0.5250730514526367f, -0.39491748809814453f,
 -0.28444138169288635f, -0.18477343022823334f, -0.09105003625154495f, 0.0f,
 0.07958029955625534f, 0.16093020141124725f, 0.24611230194568634f,
 0.33791524171829224f, 0.44070982933044434f, 0.5626170039176941f,
 0.7229568362236023f, 1.0f };

template<int N> __device__ __forceinline__ void waitv(){
    if constexpr (N == 8)      asm volatile("s_waitcnt vmcnt(8)" ::: "memory");
    else if constexpr (N == 6) asm volatile("s_waitcnt vmcnt(6)" ::: "memory");
    else if constexpr (N == 4) asm volatile("s_waitcnt vmcnt(4)" ::: "memory");
    else if constexpr (N == 3) asm volatile("s_waitcnt vmcnt(3)" ::: "memory");
    else                       asm volatile("s_waitcnt vmcnt(0)" ::: "memory");
}

// ---------------- dtype detection (u8 vs i32 idx arrays) ----------------
__global__ void k_detect(const unsigned* __restrict__ p, int* __restrict__ flag){
    if (threadIdx.x == 0){
        int u8 = 0;
        for (int i = 0; i < 256; ++i) if (p[i] >= 16u) { u8 = 1; break; }
        *flag = u8;   // 1 => bytes, 0 => int32 values
    }
}

// ---------------- NF4 dequant: idx -> f16 weights ----------------
__global__ __launch_bounds__(256) void k_dequant(const void* __restrict__ idxBase, size_t elemOff,
        const float* __restrict__ amax, f16* __restrict__ out, const int* __restrict__ flag)
{
    __shared__ __half2 T[3856];
    int t = threadIdx.x;
    if (t < 256){
        int b0 = t & 15, b1 = t >> 4;
        T[b0 + (b1 << 8)] = __halves2half2(__float2half(NF4_C[b0]), __float2half(NF4_C[b1]));
    }
    __syncthreads();
    size_t i = ((size_t)blockIdx.x * 256 + t) * 16;
    float am = amax[i >> 6];
    __half2 am2 = __float2half2_rn(am);
    union { __half2 h2[8]; uint4 u4[2]; } R;
    if (*flag){
        uint4 u = *(const uint4*)((const uint8_t*)idxBase + elemOff + i);
        unsigned w[4] = {u.x, u.y, u.z, u.w};
        #pragma unroll
        for (int j = 0; j < 4; ++j){
            R.h2[j*2+0] = __hmul2(T[w[j] & 0xFFFFu], am2);
            R.h2[j*2+1] = __hmul2(T[w[j] >> 16],     am2);
        }
    } else {
        const int4* s4 = (const int4*)((const int*)idxBase + elemOff + i);
        #pragma unroll
        for (int j = 0; j < 4; ++j){
            int4 a = s4[j];
            R.h2[j*2+0] = __hmul2(T[a.x | (a.y << 8)], am2);
            R.h2[j*2+1] = __hmul2(T[a.z | (a.w << 8)], am2);
        }
    }
    uint4* o = (uint4*)(out + i);
    o[0] = R.u4[0]; o[1] = R.u4[1];
}

// ---------------- embedding gather (fp32) ----------------
__global__ __launch_bounds__(256) void k_embed(const int* __restrict__ ids,
        const float* __restrict__ E, float* __restrict__ Hh)
{
    int row = blockIdx.x, t = threadIdx.x;
    int id = ids[row];
    const float4* s4 = (const float4*)(E + (size_t)id * D_);
    float4* d4 = (float4*)(Hh + (size_t)row * D_);
    #pragma unroll
    for (int i = 0; i < 4; ++i) d4[t + 256*i] = s4[t + 256*i];
}

// ---------------- RoPE tables ----------------
__global__ __launch_bounds__(256) void k_ropetab(float* __restrict__ cosT, float* __restrict__ sinT){
    int id = blockIdx.x * 256 + threadIdx.x;
    int d = id & 63, s = id >> 6;
    float inv = powf(500000.0f, -(float)d * (1.0f/64.0f));
    float ang = (float)s * inv;
    cosT[id] = cosf(ang);
    sinT[id] = sinf(ang);
}

// ---------------- RMSNorm (fp32 in, f16 or fp32 out) ----------------
template<int F16OUT>
__global__ __launch_bounds__(256) void k_rmsnorm(const float* __restrict__ X,
        const float* __restrict__ W, void* __restrict__ outv)
{
    int row = blockIdx.x, t = threadIdx.x;
    const float4* x4 = (const float4*)(X + (size_t)row * D_);
    float4 xs[4]; float ss = 0.f;
    #pragma unroll
    for (int i = 0; i < 4; ++i){
        xs[i] = x4[t + 256*i];
        ss += xs[i].x*xs[i].x + xs[i].y*xs[i].y + xs[i].z*xs[i].z + xs[i].w*xs[i].w;
    }
    for (int m = 32; m; m >>= 1) ss += __shfl_xor(ss, m, 64);
    __shared__ float red[4];
    if ((t & 63) == 0) red[t >> 6] = ss;
    __syncthreads();
    ss = red[0] + red[1] + red[2] + red[3];
    float rs = rsqrtf(ss * (1.0f / D_) + 1e-5f);
    #pragma unroll
    for (int i = 0; i < 4; ++i){
        int c0 = (t + 256*i) * 4;
        float4 wv = *(const float4*)(W + c0);
        float o0 = xs[i].x*rs*wv.x, o1 = xs[i].y*rs*wv.y;
        float o2 = xs[i].z*rs*wv.z, o3 = xs[i].w*rs*wv.w;
        if (F16OUT){
            f16x4 ov = { (f16)o0, (f16)o1, (f16)o2, (f16)o3 };
            *(f16x4*)((f16*)outv + (size_t)row * D_ + c0) = ov;
        } else {
            float4 ov = {o0, o1, o2, o3};
            *(float4*)((float*)outv + (size_t)row * D_ + c0) = ov;
        }
    }
}

// ---------------- RoPE apply + [b,s,h,d] -> [b,h,s,d] ----------------
template<int LNH>
__global__ __launch_bounds__(256) void k_rope(const f16* __restrict__ in, f16* __restrict__ outp,
        const float* __restrict__ cosT, const float* __restrict__ sinT)
{
    int p = blockIdx.x * 256 + threadIdx.x;
    int d = p & 63;
    int h = (p >> 6) & ((1 << LNH) - 1);
    int s = (p >> (6 + LNH)) & (S_ - 1);
    int b = p >> (16 + LNH);
    size_t ib = (((size_t)(b * S_ + s) << LNH) + (size_t)h) * HD_;
    float x1 = (float)in[ib + d], x2 = (float)in[ib + 64 + d];
    float c = cosT[s*64 + d], sn = sinT[s*64 + d];
    size_t ob = (((size_t)((b << LNH) + h)) * S_ + (size_t)s) * HD_;
    outp[ob + d]      = (f16)(x1 * c - x2 * sn);
    outp[ob + 64 + d] = (f16)(x2 * c + x1 * sn);
}

// ---------------- V: [b,s,hk,d] -> [b,hk,d,s] ----------------
__global__ __launch_bounds__(256) void k_vtrans(const f16* __restrict__ in, f16* __restrict__ outp){
    int p = blockIdx.x * 256 + threadIdx.x;
    int s  = p & (S_ - 1);
    int d  = (p >> 10) & (HD_ - 1);
    int hk = (p >> 17) & (HK_ - 1);
    int b  = p >> 20;
    f16 v = in[(((size_t)(b * S_ + s)) * HK_ + hk) * HD_ + d];
    outp[(((size_t)(b * HK_ + hk)) * HD_ + d) * S_ + s] = v;
}

// ---------------- causal softmax, in-place on f16 scores ----------------
__global__ __launch_bounds__(256) void k_softmax(__half* __restrict__ P, const int* __restrict__ amask, int bh0){
    int rid = blockIdx.x;
    int z = rid >> 10, sq = rid & (S_ - 1);
    int b = (bh0 + z) >> 5;
    __half* row = P + (size_t)z * S_ * S_ + (size_t)sq * S_;
    int t = threadIdx.x;
    const __half2* r2 = (const __half2*)row;
    __half2 a0 = r2[t*2], a1 = r2[t*2 + 1];
    float v[4] = { __low2float(a0), __high2float(a0), __low2float(a1), __high2float(a1) };
    int c0 = t * 4;
    #pragma unroll
    for (int j = 0; j < 4; ++j){
        int col = c0 + j;
        if (col > sq || amask[b * S_ + col] == 0) v[j] = -1e30f;
    }
    float mx = fmaxf(fmaxf(v[0], v[1]), fmaxf(v[2], v[3]));
    for (int m = 32; m; m >>= 1) mx = fmaxf(mx, __shfl_xor(mx, m, 64));
    __shared__ float red[4];
    if ((t & 63) == 0) red[t >> 6] = mx;
    __syncthreads();
    mx = fmaxf(fmaxf(red[0], red[1]), fmaxf(red[2], red[3]));
    float p4[4], sum = 0.f;
    #pragma unroll
    for (int j = 0; j < 4; ++j){ p4[j] = __expf(v[j] - mx); sum += p4[j]; }
    for (int m = 32; m; m >>= 1) sum += __shfl_xor(sum, m, 64);
    __syncthreads();
    if ((t & 63) == 0) red[t >> 6] = sum;
    __syncthreads();
    sum = red[0] + red[1] + red[2] + red[3];
    float inv = 1.0f / fmaxf(sum, 1e-30f);
    __half2* w2 = (__half2*)row;
    w2[t*2]     = __floats2half2_rn(p4[0]*inv, p4[1]*inv);
    w2[t*2 + 1] = __floats2half2_rn(p4[2]*inv, p4[3]*inv);
}

// ---------------- 128x128 MFMA GEMM (KV proj + attention batches) ----------------
// OUT: 2 = f16 store (scaled). BM: 0 = plain, 1 = scores batch, 2 = PV batch
template<int OUT, int BM>
__global__ __launch_bounds__(256) void k_gemm(const f16* __restrict__ A, const f16* __restrict__ Bp,
        void* __restrict__ Cv, const f16* __restrict__ G,
        int Kd, int ldc, float scale, int bh0)
{
    __shared__ f16 As[128 * 64];
    __shared__ f16 Bs[128 * 64];
    int t = threadIdx.x;
    int wave = t >> 6, lane = t & 63;
    int wr = wave >> 1, wc = wave & 1;
    int lr = lane & 15, lg = lane >> 4;
    int row0 = blockIdx.y * 128, col0 = blockIdx.x * 128;

    size_t aOff = 0, bOff = 0, cOff = 0;
    if (BM == 1){
        int bh = bh0 + blockIdx.z;
        aOff = (size_t)bh * (S_ * HD_);
        bOff = (size_t)((bh >> 5) * HK_ + ((bh & 31) >> 2)) * (S_ * HD_);
        cOff = (size_t)blockIdx.z * (S_ * S_);
    } else if (BM == 2){
        int bh = bh0 + blockIdx.z;
        aOff = (size_t)blockIdx.z * (S_ * S_);
        bOff = (size_t)((bh >> 5) * HK_ + ((bh & 31) >> 2)) * (HD_ * S_);
        cOff = (size_t)(bh >> 5) * ((size_t)S_ * D_) + (size_t)(bh & 31) * HD_;
    }

    f32x4 zero = {0.f, 0.f, 0.f, 0.f};
    f32x4 acc[4][4];
    #pragma unroll
    for (int m = 0; m < 4; ++m)
        #pragma unroll
        for (int n = 0; n < 4; ++n) acc[m][n] = zero;

    int srow = lane >> 3;
    int scol = (lane & 7) * 8;
    const f16* Abase = A  + aOff + (size_t)row0 * Kd;
    const f16* Bbase = Bp + bOff + (size_t)col0 * Kd;

    for (int k0 = 0; k0 < Kd; k0 += 64){
        if (k0) __syncthreads();
        #pragma unroll
        for (int i = 0; i < 4; ++i){
            int chunk = wave * 4 + i;
            int r = chunk * 8 + srow;
            __builtin_amdgcn_global_load_lds(AS1(Abase + (size_t)r * Kd + k0 + scol), AS3(&As[chunk * 512]), 16, 0, 0);
            __builtin_amdgcn_global_load_lds(AS1(Bbase + (size_t)r * Kd + k0 + scol), AS3(&Bs[chunk * 512]), 16, 0, 0);
        }
        __syncthreads();
        #pragma unroll
        for (int kk = 0; kk < 64; kk += 32){
            f16x8 av[4], bv[4];
            #pragma unroll
            for (int m = 0; m < 4; ++m) av[m] = *(const f16x8*)&As[(wr*64 + m*16 + lr)*64 + kk + lg*8];
            #pragma unroll
            for (int n = 0; n < 4; ++n) bv[n] = *(const f16x8*)&Bs[(wc*64 + n*16 + lr)*64 + kk + lg*8];
            #pragma unroll
            for (int m = 0; m < 4; ++m)
                #pragma unroll
                for (int n = 0; n < 4; ++n)
                    acc[m][n] = __builtin_amdgcn_mfma_f32_16x16x32_f16(av[m], bv[n], acc[m][n], 0, 0, 0);
        }
    }

    #pragma unroll
    for (int m = 0; m < 4; ++m)
    #pragma unroll
    for (int n = 0; n < 4; ++n)
    #pragma unroll
    for (int r = 0; r < 4; ++r){
        int row = row0 + wr*64 + m*16 + lg*4 + r;
        int col = col0 + wc*64 + n*16 + lr;
        size_t idx = cOff + (size_t)row * ldc + col;
        float v = acc[m][n][r] * scale;
        ((f16*)Cv)[idx] = (f16)v;
    }
}

// ---------------- 256-row pipelined MFMA GEMM (T2+T3+T4+T5 stack) ----------------
// BM=256 fixed. BN = WGN*NF*16. 512 threads = 8 waves, grid (N/BN, M/256).
// 4-slot LDS ring of BK=32 slabs, prefetch 3 ahead, counted vmcnt, XOR swizzle.
// OUT: 1 = fp32 +=, 2 = f16 store, 3 = f16 silu(G)*acc
template<int OUT, int MF, int NF, int WGM, int WGN>
__global__ __launch_bounds__(512, 2) void k_gemm2(const f16* __restrict__ A, const f16* __restrict__ Bp,
        void* __restrict__ Cv, const f16* __restrict__ G, int Kd, int ldc)
{
    constexpr int BN  = WGN * NF * 16;
    constexpr int LPT = 2 + BN / 128;       // gload_lds per thread per tile
    __shared__ f16 Asl[4 * 256 * 32];
    __shared__ f16 Bsl[4 * BN  * 32];

    const int t = threadIdx.x;
    const int w = t >> 6, l = t & 63;
    const int wm = w / WGN, wn = w % WGN;
    const int row0 = blockIdx.y * 256, col0 = blockIdx.x * BN;
    const int NT = Kd >> 5;

    // staging source addresses: chunk q=(j*512+t): row=q>>2, dest kc=t&3,
    // source kc pre-swizzled: kcs = (t&3) ^ ((row>>1)&3) = (t&3)^((t>>3)&3)
    const int kcs = (((t & 3) ^ ((t >> 3) & 3)) << 3);
    const int rr  = t >> 2;
    const f16* sA0 = A  + (size_t)(row0 + rr)       * Kd + kcs;
    const f16* sA1 = A  + (size_t)(row0 + rr + 128) * Kd + kcs;
    const f16* sB0 = Bp + (size_t)(col0 + rr)       * Kd + kcs;
    const f16* sB1 = Bp + (size_t)(col0 + rr + 128) * Kd + kcs;   // unused if BN==128
    const int dA0 = (w * 64) * 8;           // wave-uniform LDS dest (elements)
    const int dA1 = (512 + w * 64) * 8;

    // fragment LDS read offsets (swizzled): chunk = row*4 + (kc ^ ((row>>1)&3))
    int offA[MF], offB[NF];
    #pragma unroll
    for (int mf = 0; mf < MF; ++mf){
        int row = wm * (MF*16) + mf*16 + (l & 15);
        int kc  = l >> 4;
        offA[mf] = (row*4 + (kc ^ ((row >> 1) & 3))) * 8;
    }
    #pragma unroll
    for (int nf = 0; nf < NF; ++nf){
        int row = wn * (NF*16) + nf*16 + (l & 15);
        int kc  = l >> 4;
        offB[nf] = (row*4 + (kc ^ ((row >> 1) & 3))) * 8;
    }

    auto stage = [&](int Tt){
        int s2 = Tt & 3;
        size_t so = (size_t)Tt * 32;
        __builtin_amdgcn_global_load_lds(AS1(sA0 + so), AS3(&Asl[s2*8192 + dA0]), 16, 0, 0);
        __builtin_amdgcn_global_load_lds(AS1(sA1 + so), AS3(&Asl[s2*8192 + dA1]), 16, 0, 0);
        __builtin_amdgcn_global_load_lds(AS1(sB0 + so), AS3(&Bsl[s2*(BN*32) + dA0]), 16, 0, 0);
        if constexpr (BN == 256)
            __builtin_amdgcn_global_load_lds(AS1(sB1 + so), AS3(&Bsl[s2*(BN*32) + dA1]), 16, 0, 0);
    };

    f32x4 zero = {0.f, 0.f, 0.f, 0.f};
    f32x4 acc[MF][NF];
    #pragma unroll
    for (int mf = 0; mf < MF; ++mf)
        #pragma unroll
        for (int nf = 0; nf < NF; ++nf) acc[mf][nf] = zero;

    stage(0); stage(1); stage(2);
    waitv<2*LPT>();                       // tile 0 landed (own-wave)
    __builtin_amdgcn_s_barrier();         // -> tile 0 landed (all waves)

    for (int T = 0; T < NT; ++T){
        const f16* As_ = &Asl[(T & 3) * 8192];
        const f16* Bs_ = &Bsl[(T & 3) * (BN*32)];
        f16x8 av[MF], bv[NF];
        #pragma unroll
        for (int nf = 0; nf < NF; ++nf) bv[nf] = *(const f16x8*)(Bs_ + offB[nf]);
        #pragma unroll
        for (int mf = 0; mf < MF; ++mf) av[mf] = *(const f16x8*)(As_ + offA[mf]);

        if (T + 3 < NT) stage(T + 3);     // uniform branch

        int rem = NT - 2 - T;             // tiles allowed to stay in flight
        if (rem >= 2)      waitv<2*LPT>();
        else if (rem == 1) waitv<LPT>();
        else               waitv<0>();
        __builtin_amdgcn_s_barrier();     // tile T+1 now fully in LDS (all waves)

        __builtin_amdgcn_s_setprio(1);
        #pragma unroll
        for (int mf = 0; mf < MF; ++mf)
            #pragma unroll
            for (int nf = 0; nf < NF; ++nf)
                acc[mf][nf] = __builtin_amdgcn_mfma_f32_16x16x32_f16(av[mf], bv[nf], acc[mf][nf], 0, 0, 0);
        __builtin_amdgcn_s_setprio(0);
        __builtin_amdgcn_s_barrier();     // reads of slot T retired before re-stage
    }

    #pragma unroll
    for (int mf = 0; mf < MF; ++mf)
    #pragma unroll
    for (int nf = 0; nf < NF; ++nf)
    #pragma unroll
    for (int r = 0; r < 4; ++r){
        int row = row0 + wm*(MF*16) + mf*16 + ((l >> 4) << 2) + r;
        int col = col0 + wn*(NF*16) + nf*16 + (l & 15);
        size_t idx = (size_t)row * ldc + col;
        float v = acc[mf][nf][r];
        if (OUT == 1)      ((float*)Cv)[idx] += v;
        else if (OUT == 2) ((f16*)Cv)[idx] = (f16)v;
        else {
            float g = (float)G[idx];
            float sg = g / (1.f + __expf(-g));
            ((f16*)Cv)[idx] = (f16)(sg * v);
        }
    }
}

// ---------------- masked mean pool ----------------
__global__ __launch_bounds__(256) void k_pool(const float* __restrict__ Hn, const int* __restrict__ amask,
        float* __restrict__ outp)
{
    int gid = blockIdx.x * 256 + threadIdx.x;
    int b = gid >> 12, d = gid & (D_ - 1);
    float s = 0.f, cnt = 0.f;
    for (int i = 0; i < S_; ++i){
        if (amask[b * S_ + i]){
            s += Hn[((size_t)(b * S_ + i)) * D_ + d];
            cnt += 1.f;
        }
    }
    outp[gid] = s / fmaxf(cnt, 1e-9f);
}

// ---------------- launch ----------------
extern "C" void kernel_launch(void* const* d_in, const int* in_sizes, int n_in,
                              void* d_out, int out_size, void* d_ws, size_t ws_size,
                              hipStream_t stream)
{
    (void)in_sizes; (void)n_in; (void)out_size; (void)ws_size;
    const int*   ids   = (const int*)  d_in[0];
    const int*   amask = (const int*)  d_in[1];
    const float* embed = (const float*)d_in[2];
    const void*  qi = d_in[3];  const float* qa = (const float*)d_in[4];
    const void*  ki = d_in[5];  const float* ka = (const float*)d_in[6];
    const void*  vi = d_in[7];  const float* va = (const float*)d_in[8];
    const void*  oi = d_in[9];  const float* oa = (const float*)d_in[10];
    const void*  gi = d_in[11]; const float* ga = (const float*)d_in[12];
    const void*  ui = d_in[13]; const float* ua = (const float*)d_in[14];
    const void*  di = d_in[15]; const float* da = (const float*)d_in[16];
    const float* ln1 = (const float*)d_in[17];
    const float* ln2 = (const float*)d_in[18];
    const float* lnf = (const float*)d_in[19];

    const size_t DD  = (size_t)D_ * D_;
    const size_t KVD = (size_t)KV_ * D_;
    const size_t FD  = (size_t)F_ * D_;

    char* ws = (char*)d_ws;
    int*   flag = (int*)ws;
    float* h    = (float*)(ws + 256);
    float* cosT = (float*)(ws + 256 + 33554432);
    float* sinT = cosT + 65536;
    f16*   xin  = (f16*)(ws + 34078976);
    f16*   wbuf = (f16*)(ws + 50856192);
    char*  R4   = ws + 168296704;
    f16* q16 = (f16*)(R4);
    f16* k16 = (f16*)(R4 + 16777216);
    f16* v16 = (f16*)(R4 + 20971520);
    f16* qr  = (f16*)(R4 + 25165824);
    f16* kr  = (f16*)(R4 + 41943040);
    f16* vtr = (f16*)(R4 + 46137344);
    f16* ctx = (f16*)(R4 + 50331648);
    char* R5 = R4 + 67108864;
    __half* scores = (__half*)R5;
    f16*    gbuf   = (f16*)R5;
    float*  hn     = (float*)R4;

    const float ISQ = 0.08838834764831845f;

    k_detect <<<1, 64, 0, stream>>>((const unsigned*)qi, flag);
    k_embed  <<<M_, 256, 0, stream>>>(ids, embed, h);
    k_ropetab<<<256, 256, 0, stream>>>(cosT, sinT);

    for (int l = 0; l < 2; ++l){
        size_t oDD = (size_t)l * DD, oKVD = (size_t)l * KVD, oFD = (size_t)l * FD;
        k_rmsnorm<1><<<M_, 256, 0, stream>>>(h, ln1 + l * D_, xin);

        // Q / K / V projections
        k_dequant<<<DD / 4096, 256, 0, stream>>>(qi, oDD, qa + oDD/64, wbuf, flag);
        k_gemm2<2,4,4,4,2><<<dim3(D_/128, M_/256, 1), 512, 0, stream>>>(xin, wbuf, q16, nullptr, D_, D_);
        k_dequant<<<KVD / 4096, 256, 0, stream>>>(ki, oKVD, ka + oKVD/64, wbuf, flag);
        k_gemm<2,0><<<dim3(KV_/128, M_/128, 1), 256, 0, stream>>>(xin, wbuf, k16, nullptr, D_, KV_, 1.0f, 0);
        k_dequant<<<KVD / 4096, 256, 0, stream>>>(vi, oKVD, va + oKVD/64, wbuf, flag);
        k_gemm<2,0><<<dim3(KV_/128, M_/128, 1), 256, 0, stream>>>(xin, wbuf, v16, nullptr, D_, KV_, 1.0f, 0);

        // RoPE + layout changes
        k_rope<5><<<(B_*S_*H_*64)/256, 256, 0, stream>>>(q16, qr, cosT, sinT);
        k_rope<3><<<(B_*S_*HK_*64)/256, 256, 0, stream>>>(k16, kr, cosT, sinT);
        k_vtrans <<<(B_*HK_*HD_*S_)/256, 256, 0, stream>>>(v16, vtr);

        // attention in 2 chunks of 32 (b,h) pairs
        for (int c = 0; c < 2; ++c){
            k_gemm<2,1><<<dim3(S_/128, S_/128, 32), 256, 0, stream>>>(qr, kr, (void*)scores, nullptr, HD_, S_, ISQ, c*32);
            k_softmax<<<32 * S_, 256, 0, stream>>>(scores, amask, c*32);
            k_gemm<2,2><<<dim3(1, S_/128, 32), 256, 0, stream>>>((const f16*)scores, vtr, ctx, nullptr, S_, D_, 1.0f, c*32);
        }

        // O projection + residual (fp32 += into h)
        k_dequant<<<DD / 4096, 256, 0, stream>>>(oi, oDD, oa + oDD/64, wbuf, flag);
        k_gemm2<1,4,4,4,2><<<dim3(D_/128, M_/256, 1), 512, 0, stream>>>(ctx, wbuf, h, nullptr, D_, D_);

        // MLP
        k_rmsnorm<1><<<M_, 256, 0, stream>>>(h, ln2 + l * D_, xin);
        k_dequant<<<FD / 4096, 256, 0, stream>>>(gi, oFD, ga + oFD/64, wbuf, flag);
        k_gemm2<2,8,4,2,4><<<dim3(F_/256, M_/256, 1), 512, 0, stream>>>(xin, wbuf, gbuf, nullptr, D_, F_);
        k_dequant<<<FD / 4096, 256, 0, stream>>>(ui, oFD, ua + oFD/64, wbuf, flag);
        k_gemm2<3,8,4,2,4><<<dim3(F_/256, M_/256, 1), 512, 0, stream>>>(xin, wbuf, gbuf, gbuf, D_, F_);
        k_dequant<<<FD / 4096, 256, 0, stream>>>(di, oFD, da + oFD/64, wbuf, flag);
        k_gemm2<1,4,4,4,2><<<dim3(D_/128, M_/256, 1), 512, 0, stream>>>(gbuf, wbuf, h, nullptr, F_, D_);
    }

    k_rmsnorm<0><<<M_, 256, 0, stream>>>(h, lnf, hn);
    k_pool<<<(B_*D_)/256, 256, 0, stream>>>(hn, amask, (float*)d_out);
}

// Round 3
// 3217.534 us; speedup vs baseline: 1.3130x; 1.1639x over previous
//
#include <hip/hip_runtime.h>
#include <hip/hip_fp16.h>
#include <cstdint>
#include <cstddef>

// ---------------- problem constants ----------------
#define B_  2
#define S_  1024
#define D_  4096
#define KV_ 1024
#define F_  14336
#define H_  32
#define HK_ 8
#define HD_ 128
#define M_  2048   // B*S

typedef _Float16 f16;
typedef f16   f16x8 __attribute__((ext_vector_type(8)));
typedef f16   f16x4 __attribute__((ext_vector_type(4)));
typedef float f32x4 __attribute__((ext_vector_type(4)));

#define AS1(p) ((const __attribute__((address_space(1))) void*)(p))
#define AS3(p) ((__attribute__((address_space(3))) void*)(p))

__device__ __constant__ float NF4_C[16] = {
 -1.0f, -0.6961928009986877f, -0.5250730514526367f, -0.39491748809814453f,
 -0.28444138169288635f, -0.18477343022823334f, -0.09105003625154495f, 0.0f,
 0.07958029955625534f, 0.16093020141124725f, 0.24611230194568634f,
 0.33791524171829224f, 0.44070982933044434f, 0.5626170039176941f,
 0.7229568362236023f, 1.0f };

// ---------------- dtype detection (u8 vs i32 idx arrays) ----------------
__global__ void k_detect(const unsigned* __restrict__ p, int* __restrict__ flag){
    if (threadIdx.x == 0){
        int u8 = 0;
        for (int i = 0; i < 256; ++i) if (p[i] >= 16u) { u8 = 1; break; }
        *flag = u8;
    }
}

// ---------------- NF4 dequant: idx -> f16 weights ----------------
__global__ __launch_bounds__(256) void k_dequant(const void* __restrict__ idxBase, size_t elemOff,
        const float* __restrict__ amax, f16* __restrict__ out, const int* __restrict__ flag)
{
    __shared__ __half2 T[3856];
    int t = threadIdx.x;
    if (t < 256){
        int b0 = t & 15, b1 = t >> 4;
        T[b0 + (b1 << 8)] = __halves2half2(__float2half(NF4_C[b0]), __float2half(NF4_C[b1]));
    }
    __syncthreads();
    size_t i = ((size_t)blockIdx.x * 256 + t) * 16;
    float am = amax[i >> 6];
    __half2 am2 = __float2half2_rn(am);
    union { __half2 h2[8]; uint4 u4[2]; } R;
    if (*flag){
        uint4 u = *(const uint4*)((const uint8_t*)idxBase + elemOff + i);
        unsigned w[4] = {u.x, u.y, u.z, u.w};
        #pragma unroll
        for (int j = 0; j < 4; ++j){
            R.h2[j*2+0] = __hmul2(T[w[j] & 0xFFFFu], am2);
            R.h2[j*2+1] = __hmul2(T[w[j] >> 16],     am2);
        }
    } else {
        const int4* s4 = (const int4*)((const int*)idxBase + elemOff + i);
        #pragma unroll
        for (int j = 0; j < 4; ++j){
            int4 a = s4[j];
            R.h2[j*2+0] = __hmul2(T[a.x | (a.y << 8)], am2);
            R.h2[j*2+1] = __hmul2(T[a.z | (a.w << 8)], am2);
        }
    }
    uint4* o = (uint4*)(out + i);
    o[0] = R.u4[0]; o[1] = R.u4[1];
}

// ---------------- embedding gather (fp32) ----------------
__global__ __launch_bounds__(256) void k_embed(const int* __restrict__ ids,
        const float* __restrict__ E, float* __restrict__ Hh)
{
    int row = blockIdx.x, t = threadIdx.x;
    int id = ids[row];
    const float4* s4 = (const float4*)(E + (size_t)id * D_);
    float4* d4 = (float4*)(Hh + (size_t)row * D_);
    #pragma unroll
    for (int i = 0; i < 4; ++i) d4[t + 256*i] = s4[t + 256*i];
}

// ---------------- RoPE tables ----------------
__global__ __launch_bounds__(256) void k_ropetab(float* __restrict__ cosT, float* __restrict__ sinT){
    int id = blockIdx.x * 256 + threadIdx.x;
    int d = id & 63, s = id >> 6;
    float inv = powf(500000.0f, -(float)d * (1.0f/64.0f));
    float ang = (float)s * inv;
    cosT[id] = cosf(ang);
    sinT[id] = sinf(ang);
}

// ---------------- RMSNorm ----------------
template<int F16OUT>
__global__ __launch_bounds__(256) void k_rmsnorm(const float* __restrict__ X,
        const float* __restrict__ W, void* __restrict__ outv)
{
    int row = blockIdx.x, t = threadIdx.x;
    const float4* x4 = (const float4*)(X + (size_t)row * D_);
    float4 xs[4]; float ss = 0.f;
    #pragma unroll
    for (int i = 0; i < 4; ++i){
        xs[i] = x4[t + 256*i];
        ss += xs[i].x*xs[i].x + xs[i].y*xs[i].y + xs[i].z*xs[i].z + xs[i].w*xs[i].w;
    }
    for (int m = 32; m; m >>= 1) ss += __shfl_xor(ss, m, 64);
    __shared__ float red[4];
    if ((t & 63) == 0) red[t >> 6] = ss;
    __syncthreads();
    ss = red[0] + red[1] + red[2] + red[3];
    float rs = rsqrtf(ss * (1.0f / D_) + 1e-5f);
    #pragma unroll
    for (int i = 0; i < 4; ++i){
        int c0 = (t + 256*i) * 4;
        float4 wv = *(const float4*)(W + c0);
        float o0 = xs[i].x*rs*wv.x, o1 = xs[i].y*rs*wv.y;
        float o2 = xs[i].z*rs*wv.z, o3 = xs[i].w*rs*wv.w;
        if (F16OUT){
            f16x4 ov = { (f16)o0, (f16)o1, (f16)o2, (f16)o3 };
            *(f16x4*)((f16*)outv + (size_t)row * D_ + c0) = ov;
        } else {
            float4 ov = {o0, o1, o2, o3};
            *(float4*)((float*)outv + (size_t)row * D_ + c0) = ov;
        }
    }
}

// ---------------- RoPE apply + [b,s,h,d] -> [b,h,s,d] ----------------
template<int LNH>
__global__ __launch_bounds__(256) void k_rope(const f16* __restrict__ in, f16* __restrict__ outp,
        const float* __restrict__ cosT, const float* __restrict__ sinT)
{
    int p = blockIdx.x * 256 + threadIdx.x;
    int d = p & 63;
    int h = (p >> 6) & ((1 << LNH) - 1);
    int s = (p >> (6 + LNH)) & (S_ - 1);
    int b = p >> (16 + LNH);
    size_t ib = (((size_t)(b * S_ + s) << LNH) + (size_t)h) * HD_;
    float x1 = (float)in[ib + d], x2 = (float)in[ib + 64 + d];
    float c = cosT[s*64 + d], sn = sinT[s*64 + d];
    size_t ob = (((size_t)((b << LNH) + h)) * S_ + (size_t)s) * HD_;
    outp[ob + d]      = (f16)(x1 * c - x2 * sn);
    outp[ob + 64 + d] = (f16)(x2 * c + x1 * sn);
}

// ---------------- V transpose ----------------
__global__ __launch_bounds__(256) void k_vtrans(const f16* __restrict__ in, f16* __restrict__ outp){
    int p = blockIdx.x * 256 + threadIdx.x;
    int s  = p & (S_ - 1);
    int d  = (p >> 10) & (HD_ - 1);
    int hk = (p >> 17) & (HK_ - 1);
    int b  = p >> 20;
    f16 v = in[(((size_t)(b * S_ + s)) * HK_ + hk) * HD_ + d];
    outp[(((size_t)(b * HK_ + hk)) * HD_ + d) * S_ + s] = v;
}

// ---------------- causal softmax ----------------
__global__ __launch_bounds__(256) void k_softmax(__half* __restrict__ P, const int* __restrict__ amask, int bh0){
    int rid = blockIdx.x;
    int z = rid >> 10, sq = rid & (S_ - 1);
    int b = (bh0 + z) >> 5;
    __half* row = P + (size_t)z * S_ * S_ + (size_t)sq * S_;
    int t = threadIdx.x;
    const __half2* r2 = (const __half2*)row;
    __half2 a0 = r2[t*2], a1 = r2[t*2 + 1];
    float v[4] = { __low2float(a0), __high2float(a0), __low2float(a1), __high2float(a1) };
    int c0 = t * 4;
    #pragma unroll
    for (int j = 0; j < 4; ++j){
        int col = c0 + j;
        if (col > sq || amask[b * S_ + col] == 0) v[j] = -1e30f;
    }
    float mx = fmaxf(fmaxf(v[0], v[1]), fmaxf(v[2], v[3]));
    for (int m = 32; m; m >>= 1) mx = fmaxf(mx, __shfl_xor(mx, m, 64));
    __shared__ float red[4];
    if ((t & 63) == 0) red[t >> 6] = mx;
    __syncthreads();
    mx = fmaxf(fmaxf(red[0], red[1]), fmaxf(red[2], red[3]));
    float p4[4], sum = 0.f;
    #pragma unroll
    for (int j = 0; j < 4; ++j){ p4[j] = __expf(v[j] - mx); sum += p4[j]; }
    for (int m = 32; m; m >>= 1) sum += __shfl_xor(sum, m, 64);
    __syncthreads();
    if ((t & 63) == 0) red[t >> 6] = sum;
    __syncthreads();
    sum = red[0] + red[1] + red[2] + red[3];
    float inv = 1.0f / fmaxf(sum, 1e-30f);
    __half2* w2 = (__half2*)row;
    w2[t*2]     = __floats2half2_rn(p4[0]*inv, p4[1]*inv);
    w2[t*2 + 1] = __floats2half2_rn(p4[2]*inv, p4[3]*inv);
}

// ---------------- 128x128 MFMA GEMM (KV proj + attention batches) ----------------
template<int OUT, int BM>
__global__ __launch_bounds__(256) void k_gemm(const f16* __restrict__ A, const f16* __restrict__ Bp,
        void* __restrict__ Cv, const f16* __restrict__ G,
        int Kd, int ldc, float scale, int bh0)
{
    __shared__ f16 As[128 * 64];
    __shared__ f16 Bs[128 * 64];
    int t = threadIdx.x;
    int wave = t >> 6, lane = t & 63;
    int wr = wave >> 1, wc = wave & 1;
    int lr = lane & 15, lg = lane >> 4;
    int row0 = blockIdx.y * 128, col0 = blockIdx.x * 128;

    size_t aOff = 0, bOff = 0, cOff = 0;
    if (BM == 1){
        int bh = bh0 + blockIdx.z;
        aOff = (size_t)bh * (S_ * HD_);
        bOff = (size_t)((bh >> 5) * HK_ + ((bh & 31) >> 2)) * (S_ * HD_);
        cOff = (size_t)blockIdx.z * (S_ * S_);
    } else if (BM == 2){
        int bh = bh0 + blockIdx.z;
        aOff = (size_t)blockIdx.z * (S_ * S_);
        bOff = (size_t)((bh >> 5) * HK_ + ((bh & 31) >> 2)) * (HD_ * S_);
        cOff = (size_t)(bh >> 5) * ((size_t)S_ * D_) + (size_t)(bh & 31) * HD_;
    }

    f32x4 zero = {0.f, 0.f, 0.f, 0.f};
    f32x4 acc[4][4];
    #pragma unroll
    for (int m = 0; m < 4; ++m)
        #pragma unroll
        for (int n = 0; n < 4; ++n) acc[m][n] = zero;

    int srow = lane >> 3;
    int scol = (lane & 7) * 8;
    const f16* Abase = A  + aOff + (size_t)row0 * Kd;
    const f16* Bbase = Bp + bOff + (size_t)col0 * Kd;

    for (int k0 = 0; k0 < Kd; k0 += 64){
        if (k0) __syncthreads();
        #pragma unroll
        for (int i = 0; i < 4; ++i){
            int chunk = wave * 4 + i;
            int r = chunk * 8 + srow;
            __builtin_amdgcn_global_load_lds(AS1(Abase + (size_t)r * Kd + k0 + scol), AS3(&As[chunk * 512]), 16, 0, 0);
            __builtin_amdgcn_global_load_lds(AS1(Bbase + (size_t)r * Kd + k0 + scol), AS3(&Bs[chunk * 512]), 16, 0, 0);
        }
        __syncthreads();
        #pragma unroll
        for (int kk = 0; kk < 64; kk += 32){
            f16x8 av[4], bv[4];
            #pragma unroll
            for (int m = 0; m < 4; ++m) av[m] = *(const f16x8*)&As[(wr*64 + m*16 + lr)*64 + kk + lg*8];
            #pragma unroll
            for (int n = 0; n < 4; ++n) bv[n] = *(const f16x8*)&Bs[(wc*64 + n*16 + lr)*64 + kk + lg*8];
            #pragma unroll
            for (int m = 0; m < 4; ++m)
                #pragma unroll
                for (int n = 0; n < 4; ++n)
                    acc[m][n] = __builtin_amdgcn_mfma_f32_16x16x32_f16(av[m], bv[n], acc[m][n], 0, 0, 0);
        }
    }

    #pragma unroll
    for (int m = 0; m < 4; ++m)
    #pragma unroll
    for (int n = 0; n < 4; ++n)
    #pragma unroll
    for (int r = 0; r < 4; ++r){
        int row = row0 + wr*64 + m*16 + lg*4 + r;
        int col = col0 + wc*64 + n*16 + lr;
        size_t idx = cOff + (size_t)row * ldc + col;
        float v = acc[m][n][r] * scale;
        ((f16*)Cv)[idx] = (f16)v;
    }
}

// ---------------- 256x256 8-phase pipelined GEMM (m201-style T2+T3+T4+T5) ----------------
// 8 waves (2M x 4N), wave-tile 128x64, BK=64, double-buffered LDS (128 KiB).
// C computed quadrant-per-phase (16 MFMA); A/B frags held in regs across phases.
// Staging in 16KB units (2 gload_lds/thread) into retired LDS regions; vmcnt(4)
// only at phases 4 and 8. OUT: 0 = fp32 partial store (split-K via blockIdx.z),
// 2 = f16 store, 3 = f16 silu(G)*acc.
template<int OUT>
__global__ __launch_bounds__(512, 1) void k_gemm3(const f16* __restrict__ A, const f16* __restrict__ Bp,
        void* __restrict__ Cv, const f16* __restrict__ G, int Kd, int ldk, int ldc)
{
    __shared__ f16 LDS[65536];                    // A: [0,32768), B: [32768,65536)
    const int t = threadIdx.x;
    const int w = t >> 6, l = t & 63;
    const int wm = w >> 2, wn = w & 3;

    // bijective XCD swizzle (grid counts are multiples of 8)
    int gx = gridDim.x, gy = gridDim.y;
    int nWG = gx * gy * gridDim.z;
    int n = (blockIdx.z * gy + blockIdx.y) * gx + blockIdx.x;
    int q = nWG >> 3;
    int sw = (n & 7) * q + (n >> 3);
    int bx = sw % gx; int r1 = sw / gx; int by = r1 % gy; int bz = r1 / gy;

    const int row0 = by * 256, col0 = bx * 256;
    const size_t koff = (size_t)bz * Kd;
    const int NT = Kd >> 6;

    // staging source pointers (per-lane global addr, pre-swizzled K-chunk)
    const int swzk = ((t & 7) ^ ((t >> 3) & 7)) * 8;
    const f16* pA[2]; const f16* pB[2];
    #pragma unroll
    for (int l2 = 0; l2 < 2; ++l2){
        pA[l2] = A  + (size_t)(row0 + l2*128 + (t >> 3)) * ldk + koff + swzk;
        int wnc = (l2*64 + (t >> 3)) >> 5;
        pB[l2] = Bp + (size_t)(col0 + wnc*64 + ((t >> 3) & 31)) * ldk + koff + swzk;
    }

    // stage one 16KB unit: A group g of tile tt into buffer buf (and B variant)
    auto stA = [&](int g, int tt, int buf){
        size_t so = (size_t)tt * 64;
        #pragma unroll
        for (int l2 = 0; l2 < 2; ++l2)
            __builtin_amdgcn_global_load_lds(AS1(pA[l2] + (size_t)g*64*ldk + so),
                AS3(&LDS[buf*16384 + g*8192 + l2*4096 + w*512]), 16, 0, 0);
    };
    auto stB = [&](int g, int tt, int buf){
        size_t so = (size_t)tt * 64;
        #pragma unroll
        for (int l2 = 0; l2 < 2; ++l2)
            __builtin_amdgcn_global_load_lds(AS1(pB[l2] + (size_t)g*32*ldk + so),
                AS3(&LDS[32768 + buf*16384 + g*8192 + l2*4096 + w*512]), 16, 0, 0);
    };

    // LDS read lane offsets (swizzled): kphys = (ks*4 + (l>>4)) ^ (l&7)
    const int lrow = (l & 15) * 64;
    const int kp0 = (((l >> 4))     ^ (l & 7)) * 8;
    const int kp1 = ((4 + (l >> 4)) ^ (l & 7)) * 8;

    f16x8 aR[2][4], bR0[2][2], bR1[2][2];
    auto rdA = [&](int g, int buf){
        int base = buf*16384 + g*8192 + wm*4096 + lrow;
        #pragma unroll
        for (int mf = 0; mf < 4; ++mf){
            aR[0][mf] = *(const f16x8*)&LDS[base + mf*1024 + kp0];
            aR[1][mf] = *(const f16x8*)&LDS[base + mf*1024 + kp1];
        }
    };
    auto rdB = [&](int g, int buf, f16x8 (&bR)[2][2]){
        int base = 32768 + buf*16384 + g*8192 + wn*2048 + lrow;
        #pragma unroll
        for (int nf = 0; nf < 2; ++nf){
            bR[0][nf] = *(const f16x8*)&LDS[base + nf*1024 + kp0];
            bR[1][nf] = *(const f16x8*)&LDS[base + nf*1024 + kp1];
        }
    };

    f32x4 zero = {0.f, 0.f, 0.f, 0.f};
    f32x4 acc[8][4];
    #pragma unroll
    for (int mi = 0; mi < 8; ++mi)
        #pragma unroll
        for (int ni = 0; ni < 4; ++ni) acc[mi][ni] = zero;

    #define MMQ(qm, qn, bR) { \
        __builtin_amdgcn_s_setprio(1); \
        _Pragma("unroll") \
        for (int ks = 0; ks < 2; ++ks) \
            _Pragma("unroll") \
            for (int mf = 0; mf < 4; ++mf) \
                _Pragma("unroll") \
                for (int nf = 0; nf < 2; ++nf) \
                    acc[(qm)*4+mf][(qn)*2+nf] = __builtin_amdgcn_mfma_f32_16x16x32_f16(aR[ks][mf], bR[ks][nf], acc[(qm)*4+mf][(qn)*2+nf], 0, 0, 0); \
        __builtin_amdgcn_s_setprio(0); }
    #define LGKM0 { asm volatile("s_waitcnt lgkmcnt(0)" ::: "memory"); __builtin_amdgcn_sched_barrier(0); }
    #define VM4   { asm volatile("s_waitcnt vmcnt(4)" ::: "memory"); }
    #define BAR   __builtin_amdgcn_s_barrier()

    // prologue: tile0 all 4 units -> buf0; tile1 {Ag0,Bg1} -> buf1
    stA(0, 0, 0); stB(1, 0, 0); stA(1, 0, 0); stB(0, 0, 0);
    if (NT > 1){ stA(0, 1, 1); stB(1, 1, 1); }
    VM4; BAR;

    for (int tt = 0; tt < NT; tt += 2){
        int c2 = (tt + 2 < NT) ? tt + 2 : NT - 1;
        int c3 = (tt + 3 < NT) ? tt + 3 : NT - 1;
        // ---- tile tt in buf0 ----
        // ph1: quad(0,0)
        rdA(0, 0); rdB(0, 0, bR0);
        stA(1, tt+1 < NT ? tt+1 : NT-1, 1); stB(0, tt+1 < NT ? tt+1 : NT-1, 1);
        BAR; LGKM0; MMQ(0, 0, bR0); BAR;
        // ph2: quad(0,1)
        rdB(1, 0, bR1);
        BAR; LGKM0; MMQ(0, 1, bR1); BAR;
        // ph3: quad(1,1)
        rdA(1, 0);
        stA(0, c2, 0);
        BAR; LGKM0; MMQ(1, 1, bR1); BAR;
        // ph4: quad(1,0)
        stB(1, c2, 0);
        BAR; MMQ(1, 0, bR0); VM4; BAR;
        // ---- tile tt+1 in buf1 ----
        // ph5: quad(0,0)
        rdA(0, 1); rdB(0, 1, bR0);
        stA(1, c2, 0); stB(0, c2, 0);
        BAR; LGKM0; MMQ(0, 0, bR0); BAR;
        // ph6: quad(0,1)
        rdB(1, 1, bR1);
        BAR; LGKM0; MMQ(0, 1, bR1); BAR;
        // ph7: quad(1,1)
        rdA(1, 1);
        stA(0, c3, 1);
        BAR; LGKM0; MMQ(1, 1, bR1); BAR;
        // ph8: quad(1,0)
        stB(1, c3, 1);
        BAR; MMQ(1, 0, bR0); VM4; BAR;
    }

    // epilogue
    #pragma unroll
    for (int mi = 0; mi < 8; ++mi)
    #pragma unroll
    for (int ni = 0; ni < 4; ++ni)
    #pragma unroll
    for (int r = 0; r < 4; ++r){
        int row = row0 + wm*128 + mi*16 + ((l >> 4) << 2) + r;
        int col = col0 + wn*64  + ni*16 + (l & 15);
        float v = acc[mi][ni][r];
        if (OUT == 0){
            ((float*)Cv)[(size_t)bz * ((size_t)M_ * ldc) + (size_t)row * ldc + col] = v;
        } else if (OUT == 2){
            ((f16*)Cv)[(size_t)row * ldc + col] = (f16)v;
        } else {
            size_t idx = (size_t)row * ldc + col;
            float g = (float)G[idx];
            float sg = g / (1.f + __expf(-g));
            ((f16*)Cv)[idx] = (f16)(sg * v);
        }
    }
    #undef MMQ
    #undef LGKM0
    #undef VM4
    #undef BAR
}

// ---------------- split-K combine ----------------
// MODE 0: f16 out = p0+p1 ; MODE 1: fp32 h += p0+p1
template<int MODE>
__global__ __launch_bounds__(256) void k_comb(const float* __restrict__ p0, const float* __restrict__ p1,
        void* __restrict__ outv)
{
    size_t i = ((size_t)blockIdx.x * 256 + threadIdx.x) * 4;
    float4 a = *(const float4*)(p0 + i);
    float4 b = *(const float4*)(p1 + i);
    float4 s = { a.x + b.x, a.y + b.y, a.z + b.z, a.w + b.w };
    if (MODE == 0){
        f16x4 ov = { (f16)s.x, (f16)s.y, (f16)s.z, (f16)s.w };
        *(f16x4*)((f16*)outv + i) = ov;
    } else {
        float4 hv = *(const float4*)((const float*)outv + i);
        hv.x += s.x; hv.y += s.y; hv.z += s.z; hv.w += s.w;
        *(float4*)((float*)outv + i) = hv;
    }
}

// ---------------- masked mean pool ----------------
__global__ __launch_bounds__(256) void k_pool(const float* __restrict__ Hn, const int* __restrict__ amask,
        float* __restrict__ outp)
{
    int gid = blockIdx.x * 256 + threadIdx.x;
    int b = gid >> 12, d = gid & (D_ - 1);
    float s = 0.f, cnt = 0.f;
    for (int i = 0; i < S_; ++i){
        if (amask[b * S_ + i]){
            s += Hn[((size_t)(b * S_ + i)) * D_ + d];
            cnt += 1.f;
        }
    }
    outp[gid] = s / fmaxf(cnt, 1e-9f);
}

// ---------------- launch ----------------
extern "C" void kernel_launch(void* const* d_in, const int* in_sizes, int n_in,
                              void* d_out, int out_size, void* d_ws, size_t ws_size,
                              hipStream_t stream)
{
    (void)in_sizes; (void)n_in; (void)out_size; (void)ws_size;
    const int*   ids   = (const int*)  d_in[0];
    const int*   amask = (const int*)  d_in[1];
    const float* embed = (const float*)d_in[2];
    const void*  qi = d_in[3];  const float* qa = (const float*)d_in[4];
    const void*  ki = d_in[5];  const float* ka = (const float*)d_in[6];
    const void*  vi = d_in[7];  const float* va = (const float*)d_in[8];
    const void*  oi = d_in[9];  const float* oa = (const float*)d_in[10];
    const void*  gi = d_in[11]; const float* ga = (const float*)d_in[12];
    const void*  ui = d_in[13]; const float* ua = (const float*)d_in[14];
    const void*  di = d_in[15]; const float* da = (const float*)d_in[16];
    const float* ln1 = (const float*)d_in[17];
    const float* ln2 = (const float*)d_in[18];
    const float* lnf = (const float*)d_in[19];

    const size_t DD  = (size_t)D_ * D_;
    const size_t KVD = (size_t)KV_ * D_;
    const size_t FD  = (size_t)F_ * D_;

    char* ws = (char*)d_ws;
    int*   flag = (int*)ws;
    float* h    = (float*)(ws + 256);
    float* cosT = (float*)(ws + 256 + 33554432);
    float* sinT = cosT + 65536;
    f16*   xin  = (f16*)(ws + 34078976);
    f16*   wbuf = (f16*)(ws + 50856192);
    char*  R4   = ws + 168296704;
    f16* q16 = (f16*)(R4);
    f16* k16 = (f16*)(R4 + 16777216);
    f16* v16 = (f16*)(R4 + 20971520);
    f16* qr  = (f16*)(R4 + 25165824);
    f16* kr  = (f16*)(R4 + 41943040);
    f16* vtr = (f16*)(R4 + 46137344);
    f16* ctx = (f16*)(R4 + 50331648);
    char* R5 = R4 + 67108864;
    __half* scores = (__half*)R5;
    f16*    gbuf   = (f16*)R5;
    float*  pR5_0  = (float*)R5;                  // split-K partials (Q/O)
    float*  pR5_1  = (float*)(R5 + 33554432);
    float*  pR4_0  = (float*)R4;                  // split-K partials (down)
    float*  pR4_1  = (float*)(R4 + 33554432);
    float*  hn     = (float*)R4;

    const float ISQ = 0.08838834764831845f;

    k_detect <<<1, 64, 0, stream>>>((const unsigned*)qi, flag);
    k_embed  <<<M_, 256, 0, stream>>>(ids, embed, h);
    k_ropetab<<<256, 256, 0, stream>>>(cosT, sinT);

    for (int l = 0; l < 2; ++l){
        size_t oDD = (size_t)l * DD, oKVD = (size_t)l * KVD, oFD = (size_t)l * FD;
        k_rmsnorm<1><<<M_, 256, 0, stream>>>(h, ln1 + l * D_, xin);

        // Q projection (split-K x2 -> fp32 partials -> f16)
        k_dequant<<<DD / 4096, 256, 0, stream>>>(qi, oDD, qa + oDD/64, wbuf, flag);
        k_gemm3<0><<<dim3(D_/256, M_/256, 2), 512, 0, stream>>>(xin, wbuf, pR5_0, nullptr, D_/2, D_, D_);
        k_comb<0><<<(M_*D_)/1024, 256, 0, stream>>>(pR5_0, pR5_1, q16);
        // K / V projections (small N -> old kernel)
        k_dequant<<<KVD / 4096, 256, 0, stream>>>(ki, oKVD, ka + oKVD/64, wbuf, flag);
        k_gemm<2,0><<<dim3(KV_/128, M_/128, 1), 256, 0, stream>>>(xin, wbuf, k16, nullptr, D_, KV_, 1.0f, 0);
        k_dequant<<<KVD / 4096, 256, 0, stream>>>(vi, oKVD, va + oKVD/64, wbuf, flag);
        k_gemm<2,0><<<dim3(KV_/128, M_/128, 1), 256, 0, stream>>>(xin, wbuf, v16, nullptr, D_, KV_, 1.0f, 0);

        // RoPE + layout changes
        k_rope<5><<<(B_*S_*H_*64)/256, 256, 0, stream>>>(q16, qr, cosT, sinT);
        k_rope<3><<<(B_*S_*HK_*64)/256, 256, 0, stream>>>(k16, kr, cosT, sinT);
        k_vtrans <<<(B_*HK_*HD_*S_)/256, 256, 0, stream>>>(v16, vtr);

        // attention in 2 chunks of 32 (b,h) pairs
        for (int c = 0; c < 2; ++c){
            k_gemm<2,1><<<dim3(S_/128, S_/128, 32), 256, 0, stream>>>(qr, kr, (void*)scores, nullptr, HD_, S_, ISQ, c*32);
            k_softmax<<<32 * S_, 256, 0, stream>>>(scores, amask, c*32);
            k_gemm<2,2><<<dim3(1, S_/128, 32), 256, 0, stream>>>((const f16*)scores, vtr, ctx, nullptr, S_, D_, 1.0f, c*32);
        }

        // O projection + residual (split-K x2 -> h +=)
        k_dequant<<<DD / 4096, 256, 0, stream>>>(oi, oDD, oa + oDD/64, wbuf, flag);
        k_gemm3<0><<<dim3(D_/256, M_/256, 2), 512, 0, stream>>>(ctx, wbuf, pR5_0, nullptr, D_/2, D_, D_);
        k_comb<1><<<(M_*D_)/1024, 256, 0, stream>>>(pR5_0, pR5_1, h);

        // MLP
        k_rmsnorm<1><<<M_, 256, 0, stream>>>(h, ln2 + l * D_, xin);
        k_dequant<<<FD / 4096, 256, 0, stream>>>(gi, oFD, ga + oFD/64, wbuf, flag);
        k_gemm3<2><<<dim3(F_/256, M_/256, 1), 512, 0, stream>>>(xin, wbuf, gbuf, nullptr, D_, D_, F_);
        k_dequant<<<FD / 4096, 256, 0, stream>>>(ui, oFD, ua + oFD/64, wbuf, flag);
        k_gemm3<3><<<dim3(F_/256, M_/256, 1), 512, 0, stream>>>(xin, wbuf, gbuf, gbuf, D_, D_, F_);
        k_dequant<<<FD / 4096, 256, 0, stream>>>(di, oFD, da + oFD/64, wbuf, flag);
        k_gemm3<0><<<dim3(D_/256, M_/256, 2), 512, 0, stream>>>(gbuf, wbuf, pR4_0, nullptr, F_/2, F_, D_);
        k_comb<1><<<(M_*D_)/1024, 256, 0, stream>>>(pR4_0, pR4_1, h);
    }

    k_rmsnorm<0><<<M_, 256, 0, stream>>>(h, lnf, hn);
    k_pool<<<(B_*D_)/256, 256, 0, stream>>>(hn, amask, (float*)d_out);
}

// Round 4
// 2662.592 us; speedup vs baseline: 1.5867x; 1.2084x over previous
//
#include <hip/hip_runtime.h>
#include <hip/hip_fp16.h>
#include <cstdint>
#include <cstddef>

// ---------------- problem constants ----------------
#define B_  2
#define S_  1024
#define D_  4096
#define KV_ 1024
#define F_  14336
#define H_  32
#define HK_ 8
#define HD_ 128
#define M_  2048   // B*S

typedef _Float16 f16;
typedef f16   f16x8 __attribute__((ext_vector_type(8)));
typedef f16   f16x4 __attribute__((ext_vector_type(4)));
typedef float f32x4 __attribute__((ext_vector_type(4)));

#define AS1(p) ((const __attribute__((address_space(1))) void*)(p))
#define AS3(p) ((__attribute__((address_space(3))) void*)(p))

__device__ __constant__ float NF4_C[16] = {
 -1.0f, -0.6961928009986877f, -0.5250730514526367f, -0.39491748809814453f,
 -0.28444138169288635f, -0.18477343022823334f, -0.09105003625154495f, 0.0f,
 0.07958029955625534f, 0.16093020141124725f, 0.24611230194568634f,
 0.33791524171829224f, 0.44070982933044434f, 0.5626170039176941f,
 0.7229568362236023f, 1.0f };

// ---------------- dtype detection (u8 vs i32 idx arrays) ----------------
__global__ void k_detect(const unsigned* __restrict__ p, int* __restrict__ flag){
    if (threadIdx.x == 0){
        int u8 = 0;
        for (int i = 0; i < 256; ++i) if (p[i] >= 16u) { u8 = 1; break; }
        *flag = u8;
    }
}

// ---------------- NF4 dequant: idx -> f16 weights ----------------
__global__ __launch_bounds__(256) void k_dequant(const void* __restrict__ idxBase, size_t elemOff,
        const float* __restrict__ amax, f16* __restrict__ out, const int* __restrict__ flag)
{
    __shared__ __half2 T[3856];
    int t = threadIdx.x;
    if (t < 256){
        int b0 = t & 15, b1 = t >> 4;
        T[b0 + (b1 << 8)] = __halves2half2(__float2half(NF4_C[b0]), __float2half(NF4_C[b1]));
    }
    __syncthreads();
    size_t i = ((size_t)blockIdx.x * 256 + t) * 16;
    float am = amax[i >> 6];
    __half2 am2 = __float2half2_rn(am);
    union { __half2 h2[8]; uint4 u4[2]; } R;
    if (*flag){
        uint4 u = *(const uint4*)((const uint8_t*)idxBase + elemOff + i);
        unsigned w[4] = {u.x, u.y, u.z, u.w};
        #pragma unroll
        for (int j = 0; j < 4; ++j){
            R.h2[j*2+0] = __hmul2(T[w[j] & 0xFFFFu], am2);
            R.h2[j*2+1] = __hmul2(T[w[j] >> 16],     am2);
        }
    } else {
        const int4* s4 = (const int4*)((const int*)idxBase + elemOff + i);
        #pragma unroll
        for (int j = 0; j < 4; ++j){
            int4 a = s4[j];
            R.h2[j*2+0] = __hmul2(T[a.x | (a.y << 8)], am2);
            R.h2[j*2+1] = __hmul2(T[a.z | (a.w << 8)], am2);
        }
    }
    uint4* o = (uint4*)(out + i);
    o[0] = R.u4[0]; o[1] = R.u4[1];
}

// ---------------- embedding gather (fp32) ----------------
__global__ __launch_bounds__(256) void k_embed(const int* __restrict__ ids,
        const float* __restrict__ E, float* __restrict__ Hh)
{
    int row = blockIdx.x, t = threadIdx.x;
    int id = ids[row];
    const float4* s4 = (const float4*)(E + (size_t)id * D_);
    float4* d4 = (float4*)(Hh + (size_t)row * D_);
    #pragma unroll
    for (int i = 0; i < 4; ++i) d4[t + 256*i] = s4[t + 256*i];
}

// ---------------- RoPE tables ----------------
__global__ __launch_bounds__(256) void k_ropetab(float* __restrict__ cosT, float* __restrict__ sinT){
    int id = blockIdx.x * 256 + threadIdx.x;
    int d = id & 63, s = id >> 6;
    float inv = powf(500000.0f, -(float)d * (1.0f/64.0f));
    float ang = (float)s * inv;
    cosT[id] = cosf(ang);
    sinT[id] = sinf(ang);
}

// ---------------- RMSNorm ----------------
template<int F16OUT>
__global__ __launch_bounds__(256) void k_rmsnorm(const float* __restrict__ X,
        const float* __restrict__ W, void* __restrict__ outv)
{
    int row = blockIdx.x, t = threadIdx.x;
    const float4* x4 = (const float4*)(X + (size_t)row * D_);
    float4 xs[4]; float ss = 0.f;
    #pragma unroll
    for (int i = 0; i < 4; ++i){
        xs[i] = x4[t + 256*i];
        ss += xs[i].x*xs[i].x + xs[i].y*xs[i].y + xs[i].z*xs[i].z + xs[i].w*xs[i].w;
    }
    for (int m = 32; m; m >>= 1) ss += __shfl_xor(ss, m, 64);
    __shared__ float red[4];
    if ((t & 63) == 0) red[t >> 6] = ss;
    __syncthreads();
    ss = red[0] + red[1] + red[2] + red[3];
    float rs = rsqrtf(ss * (1.0f / D_) + 1e-5f);
    #pragma unroll
    for (int i = 0; i < 4; ++i){
        int c0 = (t + 256*i) * 4;
        float4 wv = *(const float4*)(W + c0);
        float o0 = xs[i].x*rs*wv.x, o1 = xs[i].y*rs*wv.y;
        float o2 = xs[i].z*rs*wv.z, o3 = xs[i].w*rs*wv.w;
        if (F16OUT){
            f16x4 ov = { (f16)o0, (f16)o1, (f16)o2, (f16)o3 };
            *(f16x4*)((f16*)outv + (size_t)row * D_ + c0) = ov;
        } else {
            float4 ov = {o0, o1, o2, o3};
            *(float4*)((float*)outv + (size_t)row * D_ + c0) = ov;
        }
    }
}

// ---------------- RoPE apply from fused QKV buffer -> [b,h,s,d] ----------------
template<int LNH>
__global__ __launch_bounds__(256) void k_rope(const f16* __restrict__ in, int istr,
        f16* __restrict__ outp, const float* __restrict__ cosT, const float* __restrict__ sinT)
{
    int p = blockIdx.x * 256 + threadIdx.x;
    int d = p & 63;
    int h = (p >> 6) & ((1 << LNH) - 1);
    int s = (p >> (6 + LNH)) & (S_ - 1);
    int b = p >> (16 + LNH);
    size_t ib = (size_t)(b * S_ + s) * istr + (size_t)h * HD_;
    float x1 = (float)in[ib + d], x2 = (float)in[ib + 64 + d];
    float c = cosT[s*64 + d], sn = sinT[s*64 + d];
    size_t ob = (((size_t)((b << LNH) + h)) * S_ + (size_t)s) * HD_;
    outp[ob + d]      = (f16)(x1 * c - x2 * sn);
    outp[ob + 64 + d] = (f16)(x2 * c + x1 * sn);
}

// ---------------- V: fused QKV buffer -> [b,hk,d,s] ----------------
__global__ __launch_bounds__(256) void k_vtrans(const f16* __restrict__ in, int istr,
        f16* __restrict__ outp){
    int p = blockIdx.x * 256 + threadIdx.x;
    int s  = p & (S_ - 1);
    int d  = (p >> 10) & (HD_ - 1);
    int hk = (p >> 17) & (HK_ - 1);
    int b  = p >> 20;
    f16 v = in[(size_t)(b * S_ + s) * istr + (size_t)hk * HD_ + d];
    outp[(((size_t)(b * HK_ + hk)) * HD_ + d) * S_ + s] = v;
}

// ---------------- causal softmax ----------------
__global__ __launch_bounds__(256) void k_softmax(__half* __restrict__ P, const int* __restrict__ amask, int bh0){
    int rid = blockIdx.x;
    int z = rid >> 10, sq = rid & (S_ - 1);
    int b = (bh0 + z) >> 5;
    __half* row = P + (size_t)z * S_ * S_ + (size_t)sq * S_;
    int t = threadIdx.x;
    const __half2* r2 = (const __half2*)row;
    __half2 a0 = r2[t*2], a1 = r2[t*2 + 1];
    float v[4] = { __low2float(a0), __high2float(a0), __low2float(a1), __high2float(a1) };
    int c0 = t * 4;
    #pragma unroll
    for (int j = 0; j < 4; ++j){
        int col = c0 + j;
        if (col > sq || amask[b * S_ + col] == 0) v[j] = -1e30f;
    }
    float mx = fmaxf(fmaxf(v[0], v[1]), fmaxf(v[2], v[3]));
    for (int m = 32; m; m >>= 1) mx = fmaxf(mx, __shfl_xor(mx, m, 64));
    __shared__ float red[4];
    if ((t & 63) == 0) red[t >> 6] = mx;
    __syncthreads();
    mx = fmaxf(fmaxf(red[0], red[1]), fmaxf(red[2], red[3]));
    float p4[4], sum = 0.f;
    #pragma unroll
    for (int j = 0; j < 4; ++j){ p4[j] = __expf(v[j] - mx); sum += p4[j]; }
    for (int m = 32; m; m >>= 1) sum += __shfl_xor(sum, m, 64);
    __syncthreads();
    if ((t & 63) == 0) red[t >> 6] = sum;
    __syncthreads();
    sum = red[0] + red[1] + red[2] + red[3];
    float inv = 1.0f / fmaxf(sum, 1e-30f);
    __half2* w2 = (__half2*)row;
    w2[t*2]     = __floats2half2_rn(p4[0]*inv, p4[1]*inv);
    w2[t*2 + 1] = __floats2half2_rn(p4[2]*inv, p4[3]*inv);
}

// ---------------- 128x128 MFMA GEMM (attention batches) ----------------
// BM: 1 = scores batch (causal early-exit), 2 = PV batch (K truncated to row0+128)
template<int OUT, int BM>
__global__ __launch_bounds__(256) void k_gemm(const f16* __restrict__ A, const f16* __restrict__ Bp,
        void* __restrict__ Cv, const f16* __restrict__ G,
        int Kd, int ldc, float scale, int bh0)
{
    __shared__ f16 As[128 * 64];
    __shared__ f16 Bs[128 * 64];
    int t = threadIdx.x;
    int wave = t >> 6, lane = t & 63;
    int wr = wave >> 1, wc = wave & 1;
    int lr = lane & 15, lg = lane >> 4;
    int row0 = blockIdx.y * 128, col0 = blockIdx.x * 128;

    size_t aOff = 0, bOff = 0, cOff = 0;
    if (BM == 1){
        if (col0 > row0 + 127) return;    // fully causal-masked tile
        int bh = bh0 + blockIdx.z;
        aOff = (size_t)bh * (S_ * HD_);
        bOff = (size_t)((bh >> 5) * HK_ + ((bh & 31) >> 2)) * (S_ * HD_);
        cOff = (size_t)blockIdx.z * (S_ * S_);
    } else if (BM == 2){
        int bh = bh0 + blockIdx.z;
        aOff = (size_t)blockIdx.z * (S_ * S_);
        bOff = (size_t)((bh >> 5) * HK_ + ((bh & 31) >> 2)) * (HD_ * S_);
        cOff = (size_t)(bh >> 5) * ((size_t)S_ * D_) + (size_t)(bh & 31) * HD_;
        Kd = row0 + 128;                  // probs beyond the causal row are exactly 0
    }

    f32x4 zero = {0.f, 0.f, 0.f, 0.f};
    f32x4 acc[4][4];
    #pragma unroll
    for (int m = 0; m < 4; ++m)
        #pragma unroll
        for (int n = 0; n < 4; ++n) acc[m][n] = zero;

    int srow = lane >> 3;
    int scol = (lane & 7) * 8;
    const f16* Abase = A  + aOff + (size_t)row0 * Kd;
    const f16* Bbase = Bp + bOff + (size_t)col0 * Kd;
    if (BM == 1){ Abase = A + aOff + (size_t)row0 * Kd; Bbase = Bp + bOff + (size_t)col0 * Kd; }
    if (BM == 2){ Abase = A + aOff + (size_t)row0 * S_; Bbase = Bp + bOff + (size_t)col0 * S_; }

    int lda = (BM == 2) ? S_ : Kd;
    for (int k0 = 0; k0 < Kd; k0 += 64){
        if (k0) __syncthreads();
        #pragma unroll
        for (int i = 0; i < 4; ++i){
            int chunk = wave * 4 + i;
            int r = chunk * 8 + srow;
            __builtin_amdgcn_global_load_lds(AS1(Abase + (size_t)r * lda + k0 + scol), AS3(&As[chunk * 512]), 16, 0, 0);
            __builtin_amdgcn_global_load_lds(AS1(Bbase + (size_t)r * lda + k0 + scol), AS3(&Bs[chunk * 512]), 16, 0, 0);
        }
        __syncthreads();
        #pragma unroll
        for (int kk = 0; kk < 64; kk += 32){
            f16x8 av[4], bv[4];
            #pragma unroll
            for (int m = 0; m < 4; ++m) av[m] = *(const f16x8*)&As[(wr*64 + m*16 + lr)*64 + kk + lg*8];
            #pragma unroll
            for (int n = 0; n < 4; ++n) bv[n] = *(const f16x8*)&Bs[(wc*64 + n*16 + lr)*64 + kk + lg*8];
            #pragma unroll
            for (int m = 0; m < 4; ++m)
                #pragma unroll
                for (int n = 0; n < 4; ++n)
                    acc[m][n] = __builtin_amdgcn_mfma_f32_16x16x32_f16(av[m], bv[n], acc[m][n], 0, 0, 0);
        }
    }

    #pragma unroll
    for (int m = 0; m < 4; ++m)
    #pragma unroll
    for (int n = 0; n < 4; ++n)
    #pragma unroll
    for (int r = 0; r < 4; ++r){
        int row = row0 + wr*64 + m*16 + lg*4 + r;
        int col = col0 + wc*64 + n*16 + lr;
        size_t idx = cOff + (size_t)row * ldc + col;
        float v = acc[m][n][r] * scale;
        ((f16*)Cv)[idx] = (f16)v;
    }
}

// ---------------- 256x256 8-phase pipelined GEMM (m201-style T2+T3+T4+T5) ----------------
template<int OUT>
__global__ __launch_bounds__(512, 1) void k_gemm3(const f16* __restrict__ A, const f16* __restrict__ Bp,
        void* __restrict__ Cv, const f16* __restrict__ G, int Kd, int ldk, int ldc)
{
    __shared__ f16 LDS[65536];                    // A: [0,32768), B: [32768,65536)
    const int t = threadIdx.x;
    const int w = t >> 6, l = t & 63;
    const int wm = w >> 2, wn = w & 3;

    int gx = gridDim.x, gy = gridDim.y;
    int nWG = gx * gy * gridDim.z;
    int n = (blockIdx.z * gy + blockIdx.y) * gx + blockIdx.x;
    int q = nWG >> 3;
    int sw = (n & 7) * q + (n >> 3);
    int bx = sw % gx; int r1 = sw / gx; int by = r1 % gy; int bz = r1 / gy;

    const int row0 = by * 256, col0 = bx * 256;
    const size_t koff = (size_t)bz * Kd;
    const int NT = Kd >> 6;

    const int swzk = ((t & 7) ^ ((t >> 3) & 7)) * 8;
    const f16* pA[2]; const f16* pB[2];
    #pragma unroll
    for (int l2 = 0; l2 < 2; ++l2){
        pA[l2] = A  + (size_t)(row0 + l2*128 + (t >> 3)) * ldk + koff + swzk;
        int wnc = (l2*64 + (t >> 3)) >> 5;
        pB[l2] = Bp + (size_t)(col0 + wnc*64 + ((t >> 3) & 31)) * ldk + koff + swzk;
    }

    auto stA = [&](int g, int tt, int buf){
        size_t so = (size_t)tt * 64;
        #pragma unroll
        for (int l2 = 0; l2 < 2; ++l2)
            __builtin_amdgcn_global_load_lds(AS1(pA[l2] + (size_t)g*64*ldk + so),
                AS3(&LDS[buf*16384 + g*8192 + l2*4096 + w*512]), 16, 0, 0);
    };
    auto stB = [&](int g, int tt, int buf){
        size_t so = (size_t)tt * 64;
        #pragma unroll
        for (int l2 = 0; l2 < 2; ++l2)
            __builtin_amdgcn_global_load_lds(AS1(pB[l2] + (size_t)g*32*ldk + so),
                AS3(&LDS[32768 + buf*16384 + g*8192 + l2*4096 + w*512]), 16, 0, 0);
    };

    const int lrow = (l & 15) * 64;
    const int kp0 = (((l >> 4))     ^ (l & 7)) * 8;
    const int kp1 = ((4 + (l >> 4)) ^ (l & 7)) * 8;

    f16x8 aR[2][4], bR0[2][2], bR1[2][2];
    auto rdA = [&](int g, int buf){
        int base = buf*16384 + g*8192 + wm*4096 + lrow;
        #pragma unroll
        for (int mf = 0; mf < 4; ++mf){
            aR[0][mf] = *(const f16x8*)&LDS[base + mf*1024 + kp0];
            aR[1][mf] = *(const f16x8*)&LDS[base + mf*1024 + kp1];
        }
    };
    auto rdB = [&](int g, int buf, f16x8 (&bR)[2][2]){
        int base = 32768 + buf*16384 + g*8192 + wn*2048 + lrow;
        #pragma unroll
        for (int nf = 0; nf < 2; ++nf){
            bR[0][nf] = *(const f16x8*)&LDS[base + nf*1024 + kp0];
            bR[1][nf] = *(const f16x8*)&LDS[base + nf*1024 + kp1];
        }
    };

    f32x4 zero = {0.f, 0.f, 0.f, 0.f};
    f32x4 acc[8][4];
    #pragma unroll
    for (int mi = 0; mi < 8; ++mi)
        #pragma unroll
        for (int ni = 0; ni < 4; ++ni) acc[mi][ni] = zero;

    #define MMQ(qm, qn, bR) { \
        __builtin_amdgcn_s_setprio(1); \
        _Pragma("unroll") \
        for (int ks = 0; ks < 2; ++ks) \
            _Pragma("unroll") \
            for (int mf = 0; mf < 4; ++mf) \
                _Pragma("unroll") \
                for (int nf = 0; nf < 2; ++nf) \
                    acc[(qm)*4+mf][(qn)*2+nf] = __builtin_amdgcn_mfma_f32_16x16x32_f16(aR[ks][mf], bR[ks][nf], acc[(qm)*4+mf][(qn)*2+nf], 0, 0, 0); \
        __builtin_amdgcn_s_setprio(0); }
    #define LGKM0 { asm volatile("s_waitcnt lgkmcnt(0)" ::: "memory"); __builtin_amdgcn_sched_barrier(0); }
    #define VM4   { asm volatile("s_waitcnt vmcnt(4)" ::: "memory"); }
    #define BAR   __builtin_amdgcn_s_barrier()

    stA(0, 0, 0); stB(1, 0, 0); stA(1, 0, 0); stB(0, 0, 0);
    if (NT > 1){ stA(0, 1, 1); stB(1, 1, 1); }
    VM4; BAR;

    for (int tt = 0; tt < NT; tt += 2){
        int c2 = (tt + 2 < NT) ? tt + 2 : NT - 1;
        int c3 = (tt + 3 < NT) ? tt + 3 : NT - 1;
        rdA(0, 0); rdB(0, 0, bR0);
        stA(1, tt+1 < NT ? tt+1 : NT-1, 1); stB(0, tt+1 < NT ? tt+1 : NT-1, 1);
        BAR; LGKM0; MMQ(0, 0, bR0); BAR;
        rdB(1, 0, bR1);
        BAR; LGKM0; MMQ(0, 1, bR1); BAR;
        rdA(1, 0);
        stA(0, c2, 0);
        BAR; LGKM0; MMQ(1, 1, bR1); BAR;
        stB(1, c2, 0);
        BAR; MMQ(1, 0, bR0); VM4; BAR;
        rdA(0, 1); rdB(0, 1, bR0);
        stA(1, c2, 0); stB(0, c2, 0);
        BAR; LGKM0; MMQ(0, 0, bR0); BAR;
        rdB(1, 1, bR1);
        BAR; LGKM0; MMQ(0, 1, bR1); BAR;
        rdA(1, 1);
        stA(0, c3, 1);
        BAR; LGKM0; MMQ(1, 1, bR1); BAR;
        stB(1, c3, 1);
        BAR; MMQ(1, 0, bR0); VM4; BAR;
    }

    #pragma unroll
    for (int mi = 0; mi < 8; ++mi)
    #pragma unroll
    for (int ni = 0; ni < 4; ++ni)
    #pragma unroll
    for (int r = 0; r < 4; ++r){
        int row = row0 + wm*128 + mi*16 + ((l >> 4) << 2) + r;
        int col = col0 + wn*64  + ni*16 + (l & 15);
        float v = acc[mi][ni][r];
        if (OUT == 0){
            ((float*)Cv)[(size_t)bz * ((size_t)M_ * ldc) + (size_t)row * ldc + col] = v;
        } else if (OUT == 2){
            ((f16*)Cv)[(size_t)row * ldc + col] = (f16)v;
        } else {
            size_t idx = (size_t)row * ldc + col;
            float g = (float)G[idx];
            float sg = g / (1.f + __expf(-g));
            ((f16*)Cv)[idx] = (f16)(sg * v);
        }
    }
    #undef MMQ
    #undef LGKM0
    #undef VM4
    #undef BAR
}

// ---------------- split-K combine: fp32 h += p0+p1 ----------------
__global__ __launch_bounds__(256) void k_comb(const float* __restrict__ p0, const float* __restrict__ p1,
        float* __restrict__ outv)
{
    size_t i = ((size_t)blockIdx.x * 256 + threadIdx.x) * 4;
    float4 a = *(const float4*)(p0 + i);
    float4 b = *(const float4*)(p1 + i);
    float4 hv = *(const float4*)(outv + i);
    hv.x += a.x + b.x; hv.y += a.y + b.y; hv.z += a.z + b.z; hv.w += a.w + b.w;
    *(float4*)(outv + i) = hv;
}

// ---------------- masked mean pool, 2-stage ----------------
__global__ __launch_bounds__(256) void k_pool1(const float* __restrict__ Hn, const int* __restrict__ amask,
        float* __restrict__ part, float* __restrict__ cntp)
{
    int d0 = blockIdx.x * 256 + threadIdx.x;     // 0..D-1
    int b  = blockIdx.y;
    int z  = blockIdx.z;                          // 0..7, 128 rows each
    int s0 = z * 128;
    float s = 0.f;
    for (int i = 0; i < 128; ++i){
        int row = s0 + i;
        if (amask[b * S_ + row])
            s += Hn[((size_t)(b * S_ + row)) * D_ + d0];
    }
    part[((size_t)(z * B_ + b)) * D_ + d0] = s;
    if (blockIdx.x == 0 && threadIdx.x == 0){
        float c = 0.f;
        for (int i = 0; i < 128; ++i) c += (amask[b * S_ + s0 + i] != 0) ? 1.f : 0.f;
        cntp[z * B_ + b] = c;
    }
}
__global__ __launch_bounds__(256) void k_pool2(const float* __restrict__ part, const float* __restrict__ cntp,
        float* __restrict__ outp)
{
    int gid = blockIdx.x * 256 + threadIdx.x;    // B*D
    int b = gid >> 12, d = gid & (D_ - 1);
    float s = 0.f, c = 0.f;
    #pragma unroll
    for (int z = 0; z < 8; ++z){
        s += part[((size_t)(z * B_ + b)) * D_ + d];
        c += cntp[z * B_ + b];
    }
    outp[gid] = s / fmaxf(c, 1e-9f);
}

// ---------------- launch ----------------
extern "C" void kernel_launch(void* const* d_in, const int* in_sizes, int n_in,
                              void* d_out, int out_size, void* d_ws, size_t ws_size,
                              hipStream_t stream)
{
    (void)in_sizes; (void)n_in; (void)out_size; (void)ws_size;
    const int*   ids   = (const int*)  d_in[0];
    const int*   amask = (const int*)  d_in[1];
    const float* embed = (const float*)d_in[2];
    const void*  qi = d_in[3];  const float* qa = (const float*)d_in[4];
    const void*  ki = d_in[5];  const float* ka = (const float*)d_in[6];
    const void*  vi = d_in[7];  const float* va = (const float*)d_in[8];
    const void*  oi = d_in[9];  const float* oa = (const float*)d_in[10];
    const void*  gi = d_in[11]; const float* ga = (const float*)d_in[12];
    const void*  ui = d_in[13]; const float* ua = (const float*)d_in[14];
    const void*  di = d_in[15]; const float* da = (const float*)d_in[16];
    const float* ln1 = (const float*)d_in[17];
    const float* ln2 = (const float*)d_in[18];
    const float* lnf = (const float*)d_in[19];

    const size_t DD  = (size_t)D_ * D_;
    const size_t KVD = (size_t)KV_ * D_;
    const size_t FD  = (size_t)F_ * D_;

    char* ws = (char*)d_ws;
    int*   flag = (int*)ws;
    float* h    = (float*)(ws + 256);
    float* cosT = (float*)(ws + 256 + 33554432);
    float* sinT = cosT + 65536;
    f16*   xin  = (f16*)(ws + 34078976);
    f16*   wbuf = (f16*)(ws + 50856192);              // up to 117 MB
    char*  R4   = ws + 168296704;
    f16* qkv16 = (f16*)(R4);                          // [M][6144] f16 = 25.2 MB
    f16* qr  = (f16*)(R4 + 25165824);
    f16* kr  = (f16*)(R4 + 41943040);
    f16* vtr = (f16*)(R4 + 46137344);
    f16* ctx = (f16*)(R4 + 50331648);
    char* R5 = R4 + 67108864;
    __half* scores = (__half*)R5;
    f16*    gbuf   = (f16*)R5;
    float*  pR5_0  = (float*)R5;                      // split-K partials (O)
    float*  pR5_1  = (float*)(R5 + 33554432);
    float*  pR4_0  = (float*)R4;                      // split-K partials (down)
    float*  pR4_1  = (float*)(R4 + 33554432);
    float*  hn     = (float*)R4;                      // final normed h
    float*  part   = (float*)R5;                      // pool partials
    float*  cntp   = (float*)(R5 + 1048576);

    const float ISQ = 0.08838834764831845f;
    const int QKV_N = D_ + 2 * KV_;                   // 6144

    k_detect <<<1, 64, 0, stream>>>((const unsigned*)qi, flag);
    k_embed  <<<M_, 256, 0, stream>>>(ids, embed, h);
    k_ropetab<<<256, 256, 0, stream>>>(cosT, sinT);

    for (int l = 0; l < 2; ++l){
        size_t oDD = (size_t)l * DD, oKVD = (size_t)l * KVD, oFD = (size_t)l * FD;
        k_rmsnorm<1><<<M_, 256, 0, stream>>>(h, ln1 + l * D_, xin);

        // fused QKV projection: weights [6144][4096], one 8-phase GEMM
        k_dequant<<<DD / 4096, 256, 0, stream>>>(qi, oDD, qa + oDD/64, wbuf, flag);
        k_dequant<<<KVD / 4096, 256, 0, stream>>>(ki, oKVD, ka + oKVD/64, wbuf + DD, flag);
        k_dequant<<<KVD / 4096, 256, 0, stream>>>(vi, oKVD, va + oKVD/64, wbuf + DD + KVD, flag);
        k_gemm3<2><<<dim3(QKV_N/256, M_/256, 1), 512, 0, stream>>>(xin, wbuf, qkv16, nullptr, D_, D_, QKV_N);

        // RoPE + layout changes (from fused buffer, row stride 6144)
        k_rope<5><<<(B_*S_*H_*64)/256, 256, 0, stream>>>(qkv16, QKV_N, qr, cosT, sinT);
        k_rope<3><<<(B_*S_*HK_*64)/256, 256, 0, stream>>>(qkv16 + D_, QKV_N, kr, cosT, sinT);
        k_vtrans <<<(B_*HK_*HD_*S_)/256, 256, 0, stream>>>(qkv16 + D_ + KV_, QKV_N, vtr);

        // attention in 2 chunks of 32 (b,h) pairs
        for (int c = 0; c < 2; ++c){
            k_gemm<2,1><<<dim3(S_/128, S_/128, 32), 256, 0, stream>>>(qr, kr, (void*)scores, nullptr, HD_, S_, ISQ, c*32);
            k_softmax<<<32 * S_, 256, 0, stream>>>(scores, amask, c*32);
            k_gemm<2,2><<<dim3(1, S_/128, 32), 256, 0, stream>>>((const f16*)scores, vtr, ctx, nullptr, S_, D_, 1.0f, c*32);
        }

        // O projection + residual (split-K x2 -> h +=)
        k_dequant<<<DD / 4096, 256, 0, stream>>>(oi, oDD, oa + oDD/64, wbuf, flag);
        k_gemm3<0><<<dim3(D_/256, M_/256, 2), 512, 0, stream>>>(ctx, wbuf, pR5_0, nullptr, D_/2, D_, D_);
        k_comb<<<(M_*D_)/1024, 256, 0, stream>>>(pR5_0, pR5_1, h);

        // MLP
        k_rmsnorm<1><<<M_, 256, 0, stream>>>(h, ln2 + l * D_, xin);
        k_dequant<<<FD / 4096, 256, 0, stream>>>(gi, oFD, ga + oFD/64, wbuf, flag);
        k_gemm3<2><<<dim3(F_/256, M_/256, 1), 512, 0, stream>>>(xin, wbuf, gbuf, nullptr, D_, D_, F_);
        k_dequant<<<FD / 4096, 256, 0, stream>>>(ui, oFD, ua + oFD/64, wbuf, flag);
        k_gemm3<3><<<dim3(F_/256, M_/256, 1), 512, 0, stream>>>(xin, wbuf, gbuf, gbuf, D_, D_, F_);
        k_dequant<<<FD / 4096, 256, 0, stream>>>(di, oFD, da + oFD/64, wbuf, flag);
        k_gemm3<0><<<dim3(D_/256, M_/256, 2), 512, 0, stream>>>(gbuf, wbuf, pR4_0, nullptr, F_/2, F_, D_);
        k_comb<<<(M_*D_)/1024, 256, 0, stream>>>(pR4_0, pR4_1, h);
    }

    k_rmsnorm<0><<<M_, 256, 0, stream>>>(h, lnf, hn);
    k_pool1<<<dim3(D_/256, B_, 8), 256, 0, stream>>>(hn, amask, part, cntp);
    k_pool2<<<(B_*D_)/256, 256, 0, stream>>>(part, cntp, (float*)d_out);
}